// Round 1
// baseline (873.756 us; speedup 1.0000x reference)
//
#include <hip/hip_runtime.h>
#include <hip/hip_bf16.h>
#include <math.h>

// ---------------- problem constants ----------------
#define N_TOK 8192          // B*T
#define C_DIM 768
#define E_NUM 8
#define H_DIM 3072
#define NROWS (N_TOK * 2)   // token-expert pairs = 16384
#define MAXT  136           // max row tiles: 16384/128 + 8

typedef unsigned short u16;
typedef __attribute__((ext_vector_type(8))) short   short8;
typedef __attribute__((ext_vector_type(8))) __bf16  bf16x8;
typedef __attribute__((ext_vector_type(4))) float   f32x4;

__device__ __forceinline__ u16 f2bf(float f) {
    __hip_bfloat16 b = __float2bfloat16(f);
    return __builtin_bit_cast(u16, b);
}

// async global->LDS DMA, 16B per lane; LDS dest is wave-uniform base + lane*16
__device__ __forceinline__ void async_copy16(void* lds, const void* g) {
    __builtin_amdgcn_global_load_lds(
        (const __attribute__((address_space(1))) void*)g,
        (__attribute__((address_space(3))) void*)lds, 16, 0, 0);
}

// ---------------- gating: 1 wave per token ----------------
__global__ void gating_kernel(const float* __restrict__ x, const float* __restrict__ gw,
                              const float* __restrict__ gb,
                              int* __restrict__ topk_idx, float* __restrict__ topk_prob,
                              int* __restrict__ counts) {
    int token = blockIdx.x;
    int lane  = threadIdx.x;
    const float* xr = x + (size_t)token * C_DIM;
    float acc[E_NUM];
#pragma unroll
    for (int e = 0; e < E_NUM; ++e) acc[e] = 0.f;
    for (int c = lane; c < C_DIM; c += 64) {
        float xv = xr[c];
#pragma unroll
        for (int e = 0; e < E_NUM; ++e) acc[e] += xv * gw[c * E_NUM + e];
    }
#pragma unroll
    for (int e = 0; e < E_NUM; ++e) {
        float v = acc[e];
        for (int off = 32; off > 0; off >>= 1) v += __shfl_down(v, off);
        acc[e] = v;
    }
    if (lane == 0) {
        float l[E_NUM];
#pragma unroll
        for (int e = 0; e < E_NUM; ++e) l[e] = acc[e] + gb[e];
        int e0 = 0;
#pragma unroll
        for (int e = 1; e < E_NUM; ++e) if (l[e] > l[e0]) e0 = e;   // first-index ties like lax.top_k
        int e1 = -1;
#pragma unroll
        for (int e = 0; e < E_NUM; ++e) if (e != e0 && (e1 < 0 || l[e] > l[e1])) e1 = e;
        // renormalized top-2 softmax == 2-way softmax of the winning logits (denominator cancels)
        float p0 = 1.f / (1.f + expf(l[e1] - l[e0]));
        topk_idx[token * 2]      = e0;
        topk_idx[token * 2 + 1]  = e1;
        topk_prob[token * 2]     = p0;
        topk_prob[token * 2 + 1] = 1.f - p0;
        atomicAdd(&counts[e0], 1);
        atomicAdd(&counts[e1], 1);
    }
}

// ---------------- bucket tables (single thread; 8 experts, trivial) ----------------
__global__ void build_tables_kernel(const int* __restrict__ counts, int* __restrict__ offsets,
                                    int* __restrict__ cursors, int* __restrict__ tile_e,
                                    int* __restrict__ tile_rs, int* __restrict__ tile_rows) {
    if (threadIdx.x != 0 || blockIdx.x != 0) return;
    int off = 0, t = 0;
    for (int e = 0; e < E_NUM; ++e) {
        offsets[e] = off;
        cursors[e] = off;
        int c = counts[e];
        for (int j = 0; j < c; j += 128) {
            tile_e[t] = e; tile_rs[t] = off + j;
            tile_rows[t] = (c - j < 128) ? (c - j) : 128;
            ++t;
        }
        off += c;
    }
    offsets[E_NUM] = off;
    for (; t < MAXT; ++t) { tile_e[t] = 0; tile_rs[t] = 0; tile_rows[t] = 0; }
}

__global__ void scatter_kernel(const int* __restrict__ topk_idx, const float* __restrict__ topk_prob,
                               int* __restrict__ cursors, int* __restrict__ row_token,
                               float* __restrict__ row_prob) {
    int i = blockIdx.x * blockDim.x + threadIdx.x;
    if (i >= NROWS) return;
    int e   = topk_idx[i];
    int pos = atomicAdd(&cursors[e], 1);
    row_token[pos] = i >> 1;
    row_prob[pos]  = topk_prob[i];
}

// out[token] := p0*b2[e0] + p1*b2[e1]  (also overwrites the 0xAA poison)
__global__ void init_out_kernel(const int* __restrict__ topk_idx, const float* __restrict__ topk_prob,
                                const float* __restrict__ b2, float* __restrict__ out) {
    int token = blockIdx.x;
    int e0 = topk_idx[token * 2], e1 = topk_idx[token * 2 + 1];
    float p0 = topk_prob[token * 2], p1 = topk_prob[token * 2 + 1];
    for (int c = threadIdx.x; c < C_DIM; c += blockDim.x)
        out[(size_t)token * C_DIM + c] = p0 * b2[e0 * C_DIM + c] + p1 * b2[e1 * C_DIM + c];
}

// ---------------- casts ----------------
__global__ void cast_x_kernel(const float* __restrict__ x, u16* __restrict__ xb) {
    int i = (blockIdx.x * blockDim.x + threadIdx.x) * 4;
    float4 v = *(const float4*)(x + i);
    u16 p[4] = {f2bf(v.x), f2bf(v.y), f2bf(v.z), f2bf(v.w)};
    *(unsigned long long*)(xb + i) = *(unsigned long long*)p;
}

// in: [E][R][C] fp32 -> out: [E][C][R] bf16   (so GEMM B-fragment k-dim is contiguous)
__global__ void transpose_cast_kernel(const float* __restrict__ in, u16* __restrict__ out,
                                      int R, int C) {
    __shared__ float tile[32][33];
    size_t mat = (size_t)R * C;
    const float* src = in + blockIdx.z * mat;
    u16* dst = out + blockIdx.z * mat;
    int c0 = blockIdx.x * 32, r0 = blockIdx.y * 32;
    int tx = threadIdx.x, ty = threadIdx.y;
#pragma unroll
    for (int i = 0; i < 4; ++i)
        tile[ty + i * 8][tx] = src[(size_t)(r0 + ty + i * 8) * C + c0 + tx];
    __syncthreads();
#pragma unroll
    for (int i = 0; i < 4; ++i)
        dst[(size_t)(c0 + ty + i * 8) * R + r0 + tx] = f2bf(tile[tx][ty + i * 8]);
}

// ---------------- GEMM1: h[r,:] = row_prob[r] * gelu(Xg[r,:] @ W1[e] + b1[e]) ----------------
// 128x128 tile, BK=64, 4 waves, 16x16x32 bf16 MFMA, global_load_lds staging.
__global__ __launch_bounds__(256) void gemm1_kernel(
    const u16* __restrict__ xb,     // [N_TOK][C]
    const u16* __restrict__ w1t,    // [E][H][C]
    const float* __restrict__ b1,   // [E][H]
    const int* __restrict__ tile_e, const int* __restrict__ tile_rs,
    const int* __restrict__ tile_nrows,
    const int* __restrict__ row_token, const float* __restrict__ row_prob,
    u16* __restrict__ h)            // [NROWS][H]
{
    const int bt = blockIdx.x;
    const int rows = tile_nrows[bt];
    if (rows == 0) return;
    const int e = tile_e[bt];
    const int row_start = tile_rs[bt];
    const int jn = blockIdx.y;      // H col tile (0..23)

    __shared__ u16 As[128 * 64];
    __shared__ u16 Bs[128 * 64];

    const int tid = threadIdx.x;
    const int lane = tid & 63;
    const int wave = tid >> 6;
    const int wm = wave & 1, wn = wave >> 1;
    const int m_in = lane & 15, quad = lane >> 4;

    const u16* a_src[4];
    const u16* b_src[4];
    int lds_off[4];
#pragma unroll
    for (int it = 0; it < 4; ++it) {
        int idx = it * 256 + tid;
        int r = idx >> 3;
        int colel = (idx & 7) * 8;
        int tok = row_token[row_start + ((r < rows) ? r : 0)];  // clamp: garbage rows masked in epilogue
        a_src[it] = xb + (size_t)tok * C_DIM + colel;
        b_src[it] = w1t + ((size_t)e * H_DIM + jn * 128 + r) * C_DIM + colel;
        lds_off[it] = r * 64 + colel;
    }

    f32x4 acc[4][4];
#pragma unroll
    for (int i = 0; i < 4; ++i)
#pragma unroll
        for (int j = 0; j < 4; ++j) acc[i][j] = (f32x4){0.f, 0.f, 0.f, 0.f};

    for (int k0 = 0; k0 < C_DIM; k0 += 64) {
#pragma unroll
        for (int it = 0; it < 4; ++it) {
            async_copy16(&As[lds_off[it]], a_src[it] + k0);
            async_copy16(&Bs[lds_off[it]], b_src[it] + k0);
        }
        __syncthreads();
#pragma unroll
        for (int ks = 0; ks < 2; ++ks) {
            bf16x8 af[4], bfr[4];
#pragma unroll
            for (int t = 0; t < 4; ++t)
                af[t] = __builtin_bit_cast(bf16x8,
                    *(const short8*)&As[(wm * 64 + t * 16 + m_in) * 64 + ks * 32 + quad * 8]);
#pragma unroll
            for (int t = 0; t < 4; ++t)
                bfr[t] = __builtin_bit_cast(bf16x8,
                    *(const short8*)&Bs[(wn * 64 + t * 16 + m_in) * 64 + ks * 32 + quad * 8]);
#pragma unroll
            for (int i = 0; i < 4; ++i)
#pragma unroll
                for (int j = 0; j < 4; ++j)
                    acc[i][j] = __builtin_amdgcn_mfma_f32_16x16x32_bf16(af[i], bfr[j], acc[i][j], 0, 0, 0);
        }
        __syncthreads();
    }

    const float* b1e = b1 + e * H_DIM + jn * 128;
#pragma unroll
    for (int i = 0; i < 4; ++i) {
#pragma unroll
        for (int r = 0; r < 4; ++r) {
            int lrow = wm * 64 + i * 16 + quad * 4 + r;
            if (lrow < rows) {
                int grow = row_start + lrow;
                float p = row_prob[grow];
#pragma unroll
                for (int j = 0; j < 4; ++j) {
                    int lcol = wn * 64 + j * 16 + m_in;
                    float v = acc[i][j][r] + b1e[lcol];
                    float g = 0.5f * v * (1.0f + erff(v * 0.70710678118654752f));  // exact gelu
                    h[(size_t)grow * H_DIM + jn * 128 + lcol] = f2bf(g * p);
                }
            }
        }
    }
}

// ---------------- GEMM2: out[token,:] += h[r,:] @ W2[e]  (atomic combine) ----------------
__global__ __launch_bounds__(256) void gemm2_kernel(
    const u16* __restrict__ h,      // [NROWS][H]
    const u16* __restrict__ w2t,    // [E][C][H]
    const int* __restrict__ tile_e, const int* __restrict__ tile_rs,
    const int* __restrict__ tile_nrows,
    const int* __restrict__ row_token,
    float* __restrict__ out)        // [N_TOK][C]
{
    const int bt = blockIdx.x;
    const int rows = tile_nrows[bt];
    if (rows == 0) return;
    const int e = tile_e[bt];
    const int row_start = tile_rs[bt];
    const int jn = blockIdx.y;      // C col tile (0..5)

    __shared__ u16 As[128 * 64];
    __shared__ u16 Bs[128 * 64];

    const int tid = threadIdx.x;
    const int lane = tid & 63;
    const int wave = tid >> 6;
    const int wm = wave & 1, wn = wave >> 1;
    const int m_in = lane & 15, quad = lane >> 4;

    const u16* a_src[4];
    const u16* b_src[4];
    int lds_off[4];
#pragma unroll
    for (int it = 0; it < 4; ++it) {
        int idx = it * 256 + tid;
        int r = idx >> 3;
        int colel = (idx & 7) * 8;
        int ar = (r < rows) ? r : 0;
        a_src[it] = h + (size_t)(row_start + ar) * H_DIM + colel;
        b_src[it] = w2t + ((size_t)e * C_DIM + jn * 128 + r) * H_DIM + colel;
        lds_off[it] = r * 64 + colel;
    }

    f32x4 acc[4][4];
#pragma unroll
    for (int i = 0; i < 4; ++i)
#pragma unroll
        for (int j = 0; j < 4; ++j) acc[i][j] = (f32x4){0.f, 0.f, 0.f, 0.f};

    for (int k0 = 0; k0 < H_DIM; k0 += 64) {
#pragma unroll
        for (int it = 0; it < 4; ++it) {
            async_copy16(&As[lds_off[it]], a_src[it] + k0);
            async_copy16(&Bs[lds_off[it]], b_src[it] + k0);
        }
        __syncthreads();
#pragma unroll
        for (int ks = 0; ks < 2; ++ks) {
            bf16x8 af[4], bfr[4];
#pragma unroll
            for (int t = 0; t < 4; ++t)
                af[t] = __builtin_bit_cast(bf16x8,
                    *(const short8*)&As[(wm * 64 + t * 16 + m_in) * 64 + ks * 32 + quad * 8]);
#pragma unroll
            for (int t = 0; t < 4; ++t)
                bfr[t] = __builtin_bit_cast(bf16x8,
                    *(const short8*)&Bs[(wn * 64 + t * 16 + m_in) * 64 + ks * 32 + quad * 8]);
#pragma unroll
            for (int i = 0; i < 4; ++i)
#pragma unroll
                for (int j = 0; j < 4; ++j)
                    acc[i][j] = __builtin_amdgcn_mfma_f32_16x16x32_bf16(af[i], bfr[j], acc[i][j], 0, 0, 0);
        }
        __syncthreads();
    }

#pragma unroll
    for (int i = 0; i < 4; ++i) {
#pragma unroll
        for (int r = 0; r < 4; ++r) {
            int lrow = wm * 64 + i * 16 + quad * 4 + r;
            if (lrow < rows) {
                int tok = row_token[row_start + lrow];
                float* orow = out + (size_t)tok * C_DIM + jn * 128;
#pragma unroll
                for (int j = 0; j < 4; ++j)
                    atomicAdd(&orow[wn * 64 + j * 16 + m_in], acc[i][j][r]);
            }
        }
    }
}

// ---------------- launch ----------------
extern "C" void kernel_launch(void* const* d_in, const int* in_sizes, int n_in,
                              void* d_out, int out_size, void* d_ws, size_t ws_size,
                              hipStream_t stream) {
    const float* x      = (const float*)d_in[0];
    const float* gate_w = (const float*)d_in[1];
    const float* gate_b = (const float*)d_in[2];
    const float* w1     = (const float*)d_in[3];
    const float* b1     = (const float*)d_in[4];
    const float* w2     = (const float*)d_in[5];
    const float* b2     = (const float*)d_in[6];
    float* out = (float*)d_out;
    char* ws = (char*)d_ws;

    // ---- workspace layout (~181 MB) ----
    int*   counts    = (int*)(ws + 0);            // 8
    int*   cursors   = (int*)(ws + 32);           // 8
    int*   offsets   = (int*)(ws + 64);           // 9
    int*   tile_e    = (int*)(ws + 128);
    int*   tile_rs   = (int*)(ws + 128 + 4 * MAXT);
    int*   tile_rows = (int*)(ws + 128 + 8 * MAXT);
    int*   topk_idx  = (int*)(ws + 4096);                    // 16384 ints
    float* topk_prob = (float*)(ws + 4096 + 65536);
    int*   row_token = (int*)(ws + 4096 + 2 * 65536);
    float* row_prob  = (float*)(ws + 4096 + 3 * 65536);
    size_t off = 1 << 20;
    u16* xb  = (u16*)(ws + off);  off += (size_t)N_TOK * C_DIM * 2;          // 12.6 MB
    u16* w1t = (u16*)(ws + off);  off += (size_t)E_NUM * C_DIM * H_DIM * 2;  // 37.7 MB
    u16* w2t = (u16*)(ws + off);  off += (size_t)E_NUM * C_DIM * H_DIM * 2;  // 37.7 MB
    u16* hbuf= (u16*)(ws + off);                                             // 100.7 MB

    hipMemsetAsync(counts, 0, 128, stream);

    cast_x_kernel<<<(N_TOK * C_DIM) / 1024, 256, 0, stream>>>(x, xb);
    transpose_cast_kernel<<<dim3(H_DIM / 32, C_DIM / 32, E_NUM), dim3(32, 8), 0, stream>>>(w1, w1t, C_DIM, H_DIM);
    transpose_cast_kernel<<<dim3(C_DIM / 32, H_DIM / 32, E_NUM), dim3(32, 8), 0, stream>>>(w2, w2t, H_DIM, C_DIM);
    gating_kernel<<<N_TOK, 64, 0, stream>>>(x, gate_w, gate_b, topk_idx, topk_prob, counts);
    build_tables_kernel<<<1, 1, 0, stream>>>(counts, offsets, cursors, tile_e, tile_rs, tile_rows);
    scatter_kernel<<<NROWS / 256, 256, 0, stream>>>(topk_idx, topk_prob, cursors, row_token, row_prob);
    init_out_kernel<<<N_TOK, 256, 0, stream>>>(topk_idx, topk_prob, b2, out);
    gemm1_kernel<<<dim3(MAXT, H_DIM / 128), 256, 0, stream>>>(xb, w1t, b1, tile_e, tile_rs, tile_rows,
                                                              row_token, row_prob, hbuf);
    gemm2_kernel<<<dim3(MAXT, C_DIM / 128), 256, 0, stream>>>(hbuf, w2t, tile_e, tile_rs, tile_rows,
                                                              row_token, out);
}

// Round 2
// 646.938 us; speedup vs baseline: 1.3506x; 1.3506x over previous
//
#include <hip/hip_runtime.h>
#include <hip/hip_bf16.h>
#include <math.h>

// ---------------- problem constants ----------------
#define N_TOK 8192          // B*T
#define C_DIM 768
#define E_NUM 8
#define H_DIM 3072
#define NROWS (N_TOK * 2)   // token-expert pairs = 16384
#define MAXT  136           // max row tiles: 16384/128 + 8
#define NBLK  64            // routing blocks (NROWS/256)

typedef unsigned short u16;
typedef __attribute__((ext_vector_type(8))) short   short8;
typedef __attribute__((ext_vector_type(8))) __bf16  bf16x8;
typedef __attribute__((ext_vector_type(4))) float   f32x4;

__device__ __forceinline__ u16 f2bf(float f) {
    __hip_bfloat16 b = __float2bfloat16(f);
    return __builtin_bit_cast(u16, b);
}

// async global->LDS DMA, 16B per lane; LDS dest is wave-uniform base + lane*16
__device__ __forceinline__ void async_copy16(void* lds, const void* g) {
    __builtin_amdgcn_global_load_lds(
        (const __attribute__((address_space(1))) void*)g,
        (__attribute__((address_space(3))) void*)lds, 16, 0, 0);
}

// ---------------- gating: 1 wave per token (no atomics) ----------------
__global__ void gating_kernel(const float* __restrict__ x, const float* __restrict__ gw,
                              const float* __restrict__ gb,
                              int* __restrict__ topk_idx, float* __restrict__ topk_prob) {
    int token = blockIdx.x;
    int lane  = threadIdx.x;
    const float* xr = x + (size_t)token * C_DIM;
    float acc[E_NUM];
#pragma unroll
    for (int e = 0; e < E_NUM; ++e) acc[e] = 0.f;
    for (int c = lane; c < C_DIM; c += 64) {
        float xv = xr[c];
#pragma unroll
        for (int e = 0; e < E_NUM; ++e) acc[e] += xv * gw[c * E_NUM + e];
    }
#pragma unroll
    for (int e = 0; e < E_NUM; ++e) {
        float v = acc[e];
        for (int off = 32; off > 0; off >>= 1) v += __shfl_down(v, off);
        acc[e] = v;
    }
    if (lane == 0) {
        float l[E_NUM];
#pragma unroll
        for (int e = 0; e < E_NUM; ++e) l[e] = acc[e] + gb[e];
        int e0 = 0;
#pragma unroll
        for (int e = 1; e < E_NUM; ++e) if (l[e] > l[e0]) e0 = e;   // first-index ties like lax.top_k
        int e1 = -1;
#pragma unroll
        for (int e = 0; e < E_NUM; ++e) if (e != e0 && (e1 < 0 || l[e] > l[e1])) e1 = e;
        // renormalized top-2 softmax == 2-way softmax of the winning logits
        float p0 = 1.f / (1.f + expf(l[e1] - l[e0]));
        topk_idx[token * 2]      = e0;
        topk_idx[token * 2 + 1]  = e1;
        topk_prob[token * 2]     = p0;
        topk_prob[token * 2 + 1] = 1.f - p0;
    }
}

// ---------------- routing: ballot histogram -> scan -> rank scatter (atomic-free) ----------------
__global__ void hist_kernel(const int* __restrict__ topk_idx, int* __restrict__ block_hist) {
    __shared__ int cnt[E_NUM];
    int tid = threadIdx.x;
    if (tid < E_NUM) cnt[tid] = 0;
    __syncthreads();
    int e = topk_idx[blockIdx.x * 256 + tid];
    int lane = tid & 63;
#pragma unroll
    for (int E = 0; E < E_NUM; ++E) {
        unsigned long long m = __ballot(e == E);
        if (lane == 0) atomicAdd(&cnt[E], __popcll(m));   // LDS atomic, 4 waves only
    }
    __syncthreads();
    if (tid < E_NUM) block_hist[blockIdx.x * E_NUM + tid] = cnt[tid];
}

__global__ void scan_tables_kernel(const int* __restrict__ block_hist,
                                   int* __restrict__ tile_e, int* __restrict__ tile_rs,
                                   int* __restrict__ tile_rows, int* __restrict__ block_base) {
    if (threadIdx.x || blockIdx.x) return;
    int counts[E_NUM], offsets[E_NUM];
    for (int e = 0; e < E_NUM; ++e) {
        int s = 0;
        for (int b = 0; b < NBLK; ++b) s += block_hist[b * E_NUM + e];
        counts[e] = s;
    }
    int off = 0;
    for (int e = 0; e < E_NUM; ++e) { offsets[e] = off; off += counts[e]; }
    for (int e = 0; e < E_NUM; ++e) {
        int s = offsets[e];
        for (int b = 0; b < NBLK; ++b) { block_base[b * E_NUM + e] = s; s += block_hist[b * E_NUM + e]; }
    }
    int t = 0;
    for (int e = 0; e < E_NUM; ++e)
        for (int j = 0; j < counts[e]; j += 128) {
            tile_e[t] = e; tile_rs[t] = offsets[e] + j;
            tile_rows[t] = (counts[e] - j < 128) ? (counts[e] - j) : 128;
            ++t;
        }
    for (; t < MAXT; ++t) { tile_e[t] = 0; tile_rs[t] = 0; tile_rows[t] = 0; }
}

__global__ void scatter_kernel(const int* __restrict__ topk_idx, const float* __restrict__ topk_prob,
                               const int* __restrict__ block_base,
                               int* __restrict__ row_token, float* __restrict__ row_prob) {
    __shared__ int wcount[4][E_NUM];
    __shared__ int wbase[4][E_NUM];
    int tid = threadIdx.x, lane = tid & 63, wave = tid >> 6;
    int idx = blockIdx.x * 256 + tid;
    int e = topk_idx[idx];
    float p = topk_prob[idx];
    int rank = 0;
    unsigned long long lt = (1ull << lane) - 1ull;
#pragma unroll
    for (int E = 0; E < E_NUM; ++E) {
        unsigned long long m = __ballot(e == E);
        if (lane == 0) wcount[wave][E] = __popcll(m);
        if (e == E) rank = __popcll(m & lt);
    }
    __syncthreads();
    if (tid < E_NUM) {
        int s = 0;
#pragma unroll
        for (int w = 0; w < 4; ++w) { wbase[w][tid] = s; s += wcount[w][tid]; }
    }
    __syncthreads();
    int pos = block_base[blockIdx.x * E_NUM + e] + wbase[wave][e] + rank;
    row_token[pos] = idx >> 1;
    row_prob[pos]  = p;
}

// out[token] := p0*b2[e0] + p1*b2[e1]  (overwrites 0xAA poison; gemm2 accumulates on top)
__global__ void init_out_kernel(const int* __restrict__ topk_idx, const float* __restrict__ topk_prob,
                                const float* __restrict__ b2, float* __restrict__ out) {
    int token = blockIdx.x;
    int e0 = topk_idx[token * 2], e1 = topk_idx[token * 2 + 1];
    float p0 = topk_prob[token * 2], p1 = topk_prob[token * 2 + 1];
    for (int c = threadIdx.x; c < C_DIM; c += blockDim.x)
        out[(size_t)token * C_DIM + c] = p0 * b2[e0 * C_DIM + c] + p1 * b2[e1 * C_DIM + c];
}

// ---------------- casts ----------------
__global__ void cast_x_kernel(const float* __restrict__ x, u16* __restrict__ xb) {
    int i = (blockIdx.x * blockDim.x + threadIdx.x) * 4;
    float4 v = *(const float4*)(x + i);
    u16 p[4] = {f2bf(v.x), f2bf(v.y), f2bf(v.z), f2bf(v.w)};
    *(unsigned long long*)(xb + i) = *(unsigned long long*)p;
}

// in: [E][R][C] fp32 -> out: [E][C][R] bf16
__global__ void transpose_cast_kernel(const float* __restrict__ in, u16* __restrict__ out,
                                      int R, int C) {
    __shared__ float tile[32][33];
    size_t mat = (size_t)R * C;
    const float* src = in + blockIdx.z * mat;
    u16* dst = out + blockIdx.z * mat;
    int c0 = blockIdx.x * 32, r0 = blockIdx.y * 32;
    int tx = threadIdx.x, ty = threadIdx.y;
#pragma unroll
    for (int i = 0; i < 4; ++i)
        tile[ty + i * 8][tx] = src[(size_t)(r0 + ty + i * 8) * C + c0 + tx];
    __syncthreads();
#pragma unroll
    for (int i = 0; i < 4; ++i)
        dst[(size_t)(c0 + ty + i * 8) * R + r0 + tx] = f2bf(tile[tx][ty + i * 8]);
}

// ============ GEMM cores: 128x128 tile, BK=64, 16x16x32 bf16 MFMA ============
// LDS XOR-swizzle: logical 16B unit u of row r lives at physical unit u^(r&7).
// DMA writes physical-contiguous (base+lane*16); lanes fetch the swizzled
// global column instead. Fragment reads then spread across all 32 banks
// (8 words/bank, balanced) instead of 16 banks (2-way serialization).

// ---------------- GEMM1: h[r,:] = row_prob[r] * gelu(Xg[r,:] @ W1[e] + b1[e]) ----------------
__global__ __launch_bounds__(256) void gemm1_kernel(
    const u16* __restrict__ xb,     // [N_TOK][C]
    const u16* __restrict__ w1t,    // [E][H][C]
    const float* __restrict__ b1,   // [E][H]
    const int* __restrict__ tile_e, const int* __restrict__ tile_rs,
    const int* __restrict__ tile_nrows,
    const int* __restrict__ row_token, const float* __restrict__ row_prob,
    u16* __restrict__ h)            // [NROWS][H]
{
    const int bt = blockIdx.x;
    const int rows = tile_nrows[bt];
    if (rows == 0) return;
    const int e = tile_e[bt];
    const int row_start = tile_rs[bt];
    const int jn = blockIdx.y;      // H col tile (0..23)

    __shared__ u16 As[128 * 64];
    __shared__ u16 Bs[128 * 64];

    const int tid = threadIdx.x;
    const int lane = tid & 63;
    const int wave = tid >> 6;
    const int wm = wave & 1, wn = wave >> 1;
    const int m_in = lane & 15, quad = lane >> 4;

    const u16* a_src[4];
    const u16* b_src[4];
    int lds_off[4];
#pragma unroll
    for (int it = 0; it < 4; ++it) {
        int idx = it * 256 + tid;
        int r = idx >> 3;
        int colel = (((idx & 7) ^ (r & 7)) * 8);            // swizzled source column
        int tok = row_token[row_start + ((r < rows) ? r : 0)];
        a_src[it] = xb + (size_t)tok * C_DIM + colel;
        b_src[it] = w1t + ((size_t)e * H_DIM + jn * 128 + r) * C_DIM + colel;
        lds_off[it] = r * 64 + (idx & 7) * 8;               // physical LDS slot
    }

    // per-lane swizzled fragment-read column offsets (elements), ks=0 / ks=1
    const int sw0 = ((quad)     ^ (m_in & 7)) * 8;
    const int sw1 = ((4 + quad) ^ (m_in & 7)) * 8;

    f32x4 acc[4][4];
#pragma unroll
    for (int i = 0; i < 4; ++i)
#pragma unroll
        for (int j = 0; j < 4; ++j) acc[i][j] = (f32x4){0.f, 0.f, 0.f, 0.f};

    for (int k0 = 0; k0 < C_DIM; k0 += 64) {
#pragma unroll
        for (int it = 0; it < 4; ++it) {
            async_copy16(&As[lds_off[it]], a_src[it] + k0);
            async_copy16(&Bs[lds_off[it]], b_src[it] + k0);
        }
        __syncthreads();
#pragma unroll
        for (int ks = 0; ks < 2; ++ks) {
            const int sw = ks ? sw1 : sw0;
            bf16x8 af[4], bfr[4];
#pragma unroll
            for (int t = 0; t < 4; ++t)
                af[t] = __builtin_bit_cast(bf16x8,
                    *(const short8*)&As[(wm * 64 + t * 16 + m_in) * 64 + sw]);
#pragma unroll
            for (int t = 0; t < 4; ++t)
                bfr[t] = __builtin_bit_cast(bf16x8,
                    *(const short8*)&Bs[(wn * 64 + t * 16 + m_in) * 64 + sw]);
#pragma unroll
            for (int i = 0; i < 4; ++i)
#pragma unroll
                for (int j = 0; j < 4; ++j)
                    acc[i][j] = __builtin_amdgcn_mfma_f32_16x16x32_bf16(af[i], bfr[j], acc[i][j], 0, 0, 0);
        }
        __syncthreads();
    }

    const float* b1e = b1 + e * H_DIM + jn * 128;
#pragma unroll
    for (int i = 0; i < 4; ++i) {
#pragma unroll
        for (int r = 0; r < 4; ++r) {
            int lrow = wm * 64 + i * 16 + quad * 4 + r;
            if (lrow < rows) {
                int grow = row_start + lrow;
                float p = row_prob[grow];
#pragma unroll
                for (int j = 0; j < 4; ++j) {
                    int lcol = wn * 64 + j * 16 + m_in;
                    float v = acc[i][j][r] + b1e[lcol];
                    float g = 0.5f * v * (1.0f + erff(v * 0.70710678118654752f));  // exact gelu
                    h[(size_t)grow * H_DIM + jn * 128 + lcol] = f2bf(g * p);
                }
            }
        }
    }
}

// ---------------- GEMM2: out[token,:] += h[r,:] @ W2[e]  (split-K, atomic combine) ----------------
#define KSPLIT 2
#define KCHUNK (H_DIM / KSPLIT)   // 1536

__global__ __launch_bounds__(256) void gemm2_kernel(
    const u16* __restrict__ h,      // [NROWS][H]
    const u16* __restrict__ w2t,    // [E][C][H]
    const int* __restrict__ tile_e, const int* __restrict__ tile_rs,
    const int* __restrict__ tile_nrows,
    const int* __restrict__ row_token,
    float* __restrict__ out)        // [N_TOK][C]
{
    const int bt = blockIdx.x;
    const int rows = tile_nrows[bt];
    if (rows == 0) return;
    const int e = tile_e[bt];
    const int row_start = tile_rs[bt];
    const int jn = blockIdx.y;      // C col tile (0..5)
    const int kz = blockIdx.z;      // K split (0..KSPLIT-1)

    __shared__ u16 As[128 * 64];
    __shared__ u16 Bs[128 * 64];

    const int tid = threadIdx.x;
    const int lane = tid & 63;
    const int wave = tid >> 6;
    const int wm = wave & 1, wn = wave >> 1;
    const int m_in = lane & 15, quad = lane >> 4;

    const u16* a_src[4];
    const u16* b_src[4];
    int lds_off[4];
#pragma unroll
    for (int it = 0; it < 4; ++it) {
        int idx = it * 256 + tid;
        int r = idx >> 3;
        int colel = (((idx & 7) ^ (r & 7)) * 8);
        int ar = (r < rows) ? r : 0;
        a_src[it] = h + (size_t)(row_start + ar) * H_DIM + colel;
        b_src[it] = w2t + ((size_t)e * C_DIM + jn * 128 + r) * H_DIM + colel;
        lds_off[it] = r * 64 + (idx & 7) * 8;
    }

    const int sw0 = ((quad)     ^ (m_in & 7)) * 8;
    const int sw1 = ((4 + quad) ^ (m_in & 7)) * 8;

    f32x4 acc[4][4];
#pragma unroll
    for (int i = 0; i < 4; ++i)
#pragma unroll
        for (int j = 0; j < 4; ++j) acc[i][j] = (f32x4){0.f, 0.f, 0.f, 0.f};

    for (int k0 = kz * KCHUNK; k0 < (kz + 1) * KCHUNK; k0 += 64) {
#pragma unroll
        for (int it = 0; it < 4; ++it) {
            async_copy16(&As[lds_off[it]], a_src[it] + k0);
            async_copy16(&Bs[lds_off[it]], b_src[it] + k0);
        }
        __syncthreads();
#pragma unroll
        for (int ks = 0; ks < 2; ++ks) {
            const int sw = ks ? sw1 : sw0;
            bf16x8 af[4], bfr[4];
#pragma unroll
            for (int t = 0; t < 4; ++t)
                af[t] = __builtin_bit_cast(bf16x8,
                    *(const short8*)&As[(wm * 64 + t * 16 + m_in) * 64 + sw]);
#pragma unroll
            for (int t = 0; t < 4; ++t)
                bfr[t] = __builtin_bit_cast(bf16x8,
                    *(const short8*)&Bs[(wn * 64 + t * 16 + m_in) * 64 + sw]);
#pragma unroll
            for (int i = 0; i < 4; ++i)
#pragma unroll
                for (int j = 0; j < 4; ++j)
                    acc[i][j] = __builtin_amdgcn_mfma_f32_16x16x32_bf16(af[i], bfr[j], acc[i][j], 0, 0, 0);
        }
        __syncthreads();
    }

#pragma unroll
    for (int i = 0; i < 4; ++i) {
#pragma unroll
        for (int r = 0; r < 4; ++r) {
            int lrow = wm * 64 + i * 16 + quad * 4 + r;
            if (lrow < rows) {
                int tok = row_token[row_start + lrow];
                float* orow = out + (size_t)tok * C_DIM + jn * 128;
#pragma unroll
                for (int j = 0; j < 4; ++j)
                    atomicAdd(&orow[wn * 64 + j * 16 + m_in], acc[i][j][r]);
            }
        }
    }
}

// ---------------- launch ----------------
extern "C" void kernel_launch(void* const* d_in, const int* in_sizes, int n_in,
                              void* d_out, int out_size, void* d_ws, size_t ws_size,
                              hipStream_t stream) {
    const float* x      = (const float*)d_in[0];
    const float* gate_w = (const float*)d_in[1];
    const float* gate_b = (const float*)d_in[2];
    const float* w1     = (const float*)d_in[3];
    const float* b1     = (const float*)d_in[4];
    const float* w2     = (const float*)d_in[5];
    const float* b2     = (const float*)d_in[6];
    float* out = (float*)d_out;
    char* ws = (char*)d_ws;

    // ---- workspace layout (~181 MB) ----
    int*   tile_e     = (int*)(ws + 0);
    int*   tile_rs    = (int*)(ws + 1024);
    int*   tile_rows  = (int*)(ws + 2048);
    int*   topk_idx   = (int*)(ws + 4096);
    float* topk_prob  = (float*)(ws + 4096 + 65536);
    int*   row_token  = (int*)(ws + 4096 + 2 * 65536);
    float* row_prob   = (float*)(ws + 4096 + 3 * 65536);
    int*   block_hist = (int*)(ws + 4096 + 4 * 65536);
    int*   block_base = (int*)(ws + 4096 + 4 * 65536 + 2048);
    size_t off = 1 << 20;
    u16* xb  = (u16*)(ws + off);  off += (size_t)N_TOK * C_DIM * 2;          // 12.6 MB
    u16* w1t = (u16*)(ws + off);  off += (size_t)E_NUM * C_DIM * H_DIM * 2;  // 37.7 MB
    u16* w2t = (u16*)(ws + off);  off += (size_t)E_NUM * C_DIM * H_DIM * 2;  // 37.7 MB
    u16* hbuf= (u16*)(ws + off);                                             // 100.7 MB

    cast_x_kernel<<<(N_TOK * C_DIM) / 1024, 256, 0, stream>>>(x, xb);
    transpose_cast_kernel<<<dim3(H_DIM / 32, C_DIM / 32, E_NUM), dim3(32, 8), 0, stream>>>(w1, w1t, C_DIM, H_DIM);
    transpose_cast_kernel<<<dim3(C_DIM / 32, H_DIM / 32, E_NUM), dim3(32, 8), 0, stream>>>(w2, w2t, H_DIM, C_DIM);
    gating_kernel<<<N_TOK, 64, 0, stream>>>(x, gate_w, gate_b, topk_idx, topk_prob);
    hist_kernel<<<NBLK, 256, 0, stream>>>(topk_idx, block_hist);
    scan_tables_kernel<<<1, 1, 0, stream>>>(block_hist, tile_e, tile_rs, tile_rows, block_base);
    scatter_kernel<<<NBLK, 256, 0, stream>>>(topk_idx, topk_prob, block_base, row_token, row_prob);
    init_out_kernel<<<N_TOK, 256, 0, stream>>>(topk_idx, topk_prob, b2, out);
    gemm1_kernel<<<dim3(MAXT, H_DIM / 128), 256, 0, stream>>>(xb, w1t, b1, tile_e, tile_rs, tile_rows,
                                                              row_token, row_prob, hbuf);
    gemm2_kernel<<<dim3(MAXT, C_DIM / 128, KSPLIT), 256, 0, stream>>>(hbuf, w2t, tile_e, tile_rs, tile_rows,
                                                                      row_token, out);
}

// Round 3
// 547.238 us; speedup vs baseline: 1.5967x; 1.1822x over previous
//
#include <hip/hip_runtime.h>
#include <hip/hip_bf16.h>
#include <math.h>

// ---------------- problem constants ----------------
#define N_TOK 8192          // B*T
#define C_DIM 768
#define E_NUM 8
#define H_DIM 3072
#define NROWS (N_TOK * 2)   // token-expert pairs = 16384
#define MAXT1 72            // gemm1 row tiles of 256: 16384/256 + 8
#define MAXT2 136           // gemm2 row tiles of 128: 16384/128 + 8
#define NBLK  64            // routing blocks (NROWS/256)

typedef unsigned short u16;
typedef __attribute__((ext_vector_type(8))) short   short8;
typedef __attribute__((ext_vector_type(8))) __bf16  bf16x8;
typedef __attribute__((ext_vector_type(4))) float   f32x4;

__device__ __forceinline__ u16 f2bf(float f) {
    __hip_bfloat16 b = __float2bfloat16(f);
    return __builtin_bit_cast(u16, b);
}
__device__ __forceinline__ float bf2f(u16 u) {
    unsigned int v = ((unsigned int)u) << 16;
    return __builtin_bit_cast(float, v);
}

// async global->LDS DMA, 16B per lane; LDS dest is wave-uniform base + lane*16
__device__ __forceinline__ void async_copy16(void* lds, const void* g) {
    __builtin_amdgcn_global_load_lds(
        (const __attribute__((address_space(1))) void*)g,
        (__attribute__((address_space(3))) void*)lds, 16, 0, 0);
}

// ---------------- gating: 1 wave per token (no atomics) ----------------
__global__ void gating_kernel(const float* __restrict__ x, const float* __restrict__ gw,
                              const float* __restrict__ gb,
                              int* __restrict__ topk_idx, float* __restrict__ topk_prob) {
    int token = blockIdx.x;
    int lane  = threadIdx.x;
    const float* xr = x + (size_t)token * C_DIM;
    float acc[E_NUM];
#pragma unroll
    for (int e = 0; e < E_NUM; ++e) acc[e] = 0.f;
    for (int c = lane; c < C_DIM; c += 64) {
        float xv = xr[c];
#pragma unroll
        for (int e = 0; e < E_NUM; ++e) acc[e] += xv * gw[c * E_NUM + e];
    }
#pragma unroll
    for (int e = 0; e < E_NUM; ++e) {
        float v = acc[e];
        for (int off = 32; off > 0; off >>= 1) v += __shfl_down(v, off);
        acc[e] = v;
    }
    if (lane == 0) {
        float l[E_NUM];
#pragma unroll
        for (int e = 0; e < E_NUM; ++e) l[e] = acc[e] + gb[e];
        int e0 = 0;
#pragma unroll
        for (int e = 1; e < E_NUM; ++e) if (l[e] > l[e0]) e0 = e;   // first-index ties like lax.top_k
        int e1 = -1;
#pragma unroll
        for (int e = 0; e < E_NUM; ++e) if (e != e0 && (e1 < 0 || l[e] > l[e1])) e1 = e;
        // renormalized top-2 softmax == 2-way softmax of the winning logits
        float p0 = 1.f / (1.f + expf(l[e1] - l[e0]));
        topk_idx[token * 2]      = e0;
        topk_idx[token * 2 + 1]  = e1;
        topk_prob[token * 2]     = p0;
        topk_prob[token * 2 + 1] = 1.f - p0;
    }
}

// ---------------- routing: ballot histogram -> scan -> rank scatter (atomic-free) ----------------
__global__ void hist_kernel(const int* __restrict__ topk_idx, int* __restrict__ block_hist) {
    __shared__ int cnt[E_NUM];
    int tid = threadIdx.x;
    if (tid < E_NUM) cnt[tid] = 0;
    __syncthreads();
    int e = topk_idx[blockIdx.x * 256 + tid];
    int lane = tid & 63;
#pragma unroll
    for (int E = 0; E < E_NUM; ++E) {
        unsigned long long m = __ballot(e == E);
        if (lane == 0) atomicAdd(&cnt[E], __popcll(m));   // LDS atomic, 4 waves only
    }
    __syncthreads();
    if (tid < E_NUM) block_hist[blockIdx.x * E_NUM + tid] = cnt[tid];
}

__global__ void scan_tables_kernel(const int* __restrict__ block_hist,
                                   int* __restrict__ t1_e, int* __restrict__ t1_rs, int* __restrict__ t1_rows,
                                   int* __restrict__ t2_e, int* __restrict__ t2_rs, int* __restrict__ t2_rows,
                                   int* __restrict__ block_base) {
    if (threadIdx.x || blockIdx.x) return;
    int counts[E_NUM], offsets[E_NUM];
    for (int e = 0; e < E_NUM; ++e) {
        int s = 0;
        for (int b = 0; b < NBLK; ++b) s += block_hist[b * E_NUM + e];
        counts[e] = s;
    }
    int off = 0;
    for (int e = 0; e < E_NUM; ++e) { offsets[e] = off; off += counts[e]; }
    for (int e = 0; e < E_NUM; ++e) {
        int s = offsets[e];
        for (int b = 0; b < NBLK; ++b) { block_base[b * E_NUM + e] = s; s += block_hist[b * E_NUM + e]; }
    }
    // 256-row tiles for gemm1
    int t = 0;
    for (int e = 0; e < E_NUM; ++e)
        for (int j = 0; j < counts[e]; j += 256) {
            t1_e[t] = e; t1_rs[t] = offsets[e] + j;
            t1_rows[t] = (counts[e] - j < 256) ? (counts[e] - j) : 256;
            ++t;
        }
    for (; t < MAXT1; ++t) { t1_e[t] = 0; t1_rs[t] = 0; t1_rows[t] = 0; }
    // 128-row tiles for gemm2
    t = 0;
    for (int e = 0; e < E_NUM; ++e)
        for (int j = 0; j < counts[e]; j += 128) {
            t2_e[t] = e; t2_rs[t] = offsets[e] + j;
            t2_rows[t] = (counts[e] - j < 128) ? (counts[e] - j) : 128;
            ++t;
        }
    for (; t < MAXT2; ++t) { t2_e[t] = 0; t2_rs[t] = 0; t2_rows[t] = 0; }
}

__global__ void scatter_kernel(const int* __restrict__ topk_idx, const float* __restrict__ topk_prob,
                               const int* __restrict__ block_base,
                               int* __restrict__ row_token, float* __restrict__ row_prob,
                               int* __restrict__ tok2row) {
    __shared__ int wcount[4][E_NUM];
    __shared__ int wbase[4][E_NUM];
    int tid = threadIdx.x, lane = tid & 63, wave = tid >> 6;
    int idx = blockIdx.x * 256 + tid;
    int e = topk_idx[idx];
    float p = topk_prob[idx];
    int rank = 0;
    unsigned long long lt = (1ull << lane) - 1ull;
#pragma unroll
    for (int E = 0; E < E_NUM; ++E) {
        unsigned long long m = __ballot(e == E);
        if (lane == 0) wcount[wave][E] = __popcll(m);
        if (e == E) rank = __popcll(m & lt);
    }
    __syncthreads();
    if (tid < E_NUM) {
        int s = 0;
#pragma unroll
        for (int w = 0; w < 4; ++w) { wbase[w][tid] = s; s += wcount[w][tid]; }
    }
    __syncthreads();
    int pos = block_base[blockIdx.x * E_NUM + e] + wbase[wave][e] + rank;
    row_token[pos] = idx >> 1;
    row_prob[pos]  = p;
    tok2row[idx]   = pos;
}

// ---------------- casts ----------------
__global__ void cast_x_kernel(const float* __restrict__ x, u16* __restrict__ xb) {
    int i = (blockIdx.x * blockDim.x + threadIdx.x) * 4;
    float4 v = *(const float4*)(x + i);
    u16 p[4] = {f2bf(v.x), f2bf(v.y), f2bf(v.z), f2bf(v.w)};
    *(unsigned long long*)(xb + i) = *(unsigned long long*)p;
}

// in: [E][R][C] fp32 -> out: [E][C][R] bf16
__global__ void transpose_cast_kernel(const float* __restrict__ in, u16* __restrict__ out,
                                      int R, int C) {
    __shared__ float tile[32][33];
    size_t mat = (size_t)R * C;
    const float* src = in + blockIdx.z * mat;
    u16* dst = out + blockIdx.z * mat;
    int c0 = blockIdx.x * 32, r0 = blockIdx.y * 32;
    int tx = threadIdx.x, ty = threadIdx.y;
#pragma unroll
    for (int i = 0; i < 4; ++i)
        tile[ty + i * 8][tx] = src[(size_t)(r0 + ty + i * 8) * C + c0 + tx];
    __syncthreads();
#pragma unroll
    for (int i = 0; i < 4; ++i)
        dst[(size_t)(c0 + ty + i * 8) * R + r0 + tx] = f2bf(tile[tx][ty + i * 8]);
}

// ============ GEMM cores: BK=64, 16x16x32 bf16 MFMA, XOR-swizzled LDS ============
// Swizzle: logical 16B unit u of row r lives at physical unit u^(r&7); DMA writes
// physical-contiguous (base+lane*16), lanes fetch the swizzled global column.

// ---------------- GEMM1: 256x128 tile, 8 waves ----------------
// h[r,:] = row_prob[r] * gelu(Xg[r,:] @ W1[e] + b1[e])
__global__ __launch_bounds__(512) void gemm1_kernel(
    const u16* __restrict__ xb,     // [N_TOK][C]
    const u16* __restrict__ w1t,    // [E][H][C]
    const float* __restrict__ b1,   // [E][H]
    const int* __restrict__ tile_e, const int* __restrict__ tile_rs,
    const int* __restrict__ tile_nrows,
    const int* __restrict__ row_token, const float* __restrict__ row_prob,
    u16* __restrict__ h)            // [NROWS][H]
{
    const int bt = blockIdx.x;
    const int rows = tile_nrows[bt];
    if (rows == 0) return;
    const int e = tile_e[bt];
    const int row_start = tile_rs[bt];
    const int jn = blockIdx.y;      // H col tile (0..23)

    __shared__ u16 As[256 * 64];    // 32 KB
    __shared__ u16 Bs[128 * 64];    // 16 KB

    const int tid = threadIdx.x;
    const int lane = tid & 63;
    const int wave = tid >> 6;
    const int wm = wave & 3, wn = wave >> 2;   // 4 m-subtiles x 2 n-subtiles of 64
    const int m_in = lane & 15, quad = lane >> 4;

    const u16* a_src[8];
    const u16* b_src[4];
#pragma unroll
    for (int it = 0; it < 8; ++it) {
        int idx = it * 512 + tid;                 // 0..4095 covers 256 rows x 64 cols /8
        int r = idx >> 3;
        int colel = (((idx & 7) ^ (r & 7)) * 8);  // swizzled source column
        int tok = row_token[row_start + ((r < rows) ? r : 0)];
        a_src[it] = xb + (size_t)tok * C_DIM + colel;
    }
#pragma unroll
    for (int it = 0; it < 2; ++it) {
        int idx = it * 512 + tid;                 // 0..1023 covers 128 rows x 64 cols /8
        int r = idx >> 3;
        int colel = (((idx & 7) ^ (r & 7)) * 8);
        b_src[it] = w1t + ((size_t)e * H_DIM + jn * 128 + r) * C_DIM + colel;
    }

    const int sw0 = ((quad)     ^ (m_in & 7)) * 8;
    const int sw1 = ((4 + quad) ^ (m_in & 7)) * 8;

    f32x4 acc[4][4];
#pragma unroll
    for (int i = 0; i < 4; ++i)
#pragma unroll
        for (int j = 0; j < 4; ++j) acc[i][j] = (f32x4){0.f, 0.f, 0.f, 0.f};

    for (int k0 = 0; k0 < C_DIM; k0 += 64) {
#pragma unroll
        for (int it = 0; it < 8; ++it)
            async_copy16(&As[(it * 512 + tid) * 8], a_src[it] + k0);
#pragma unroll
        for (int it = 0; it < 2; ++it)
            async_copy16(&Bs[(it * 512 + tid) * 8], b_src[it] + k0);
        __syncthreads();
#pragma unroll
        for (int ks = 0; ks < 2; ++ks) {
            const int sw = ks ? sw1 : sw0;
            bf16x8 af[4], bfr[4];
#pragma unroll
            for (int t = 0; t < 4; ++t)
                af[t] = __builtin_bit_cast(bf16x8,
                    *(const short8*)&As[(wm * 64 + t * 16 + m_in) * 64 + sw]);
#pragma unroll
            for (int t = 0; t < 4; ++t)
                bfr[t] = __builtin_bit_cast(bf16x8,
                    *(const short8*)&Bs[(wn * 64 + t * 16 + m_in) * 64 + sw]);
#pragma unroll
            for (int i = 0; i < 4; ++i)
#pragma unroll
                for (int j = 0; j < 4; ++j)
                    acc[i][j] = __builtin_amdgcn_mfma_f32_16x16x32_bf16(af[i], bfr[j], acc[i][j], 0, 0, 0);
        }
        __syncthreads();
    }

    const float* b1e = b1 + e * H_DIM + jn * 128;
#pragma unroll
    for (int i = 0; i < 4; ++i) {
#pragma unroll
        for (int r = 0; r < 4; ++r) {
            int lrow = wm * 64 + i * 16 + quad * 4 + r;
            if (lrow < rows) {
                int grow = row_start + lrow;
                float p = row_prob[grow];
#pragma unroll
                for (int j = 0; j < 4; ++j) {
                    int lcol = wn * 64 + j * 16 + m_in;
                    float v = acc[i][j][r] + b1e[lcol];
                    float g = 0.5f * v * (1.0f + erff(v * 0.70710678118654752f));  // exact gelu
                    h[(size_t)grow * H_DIM + jn * 128 + lcol] = f2bf(g * p);
                }
            }
        }
    }
}

// ---------------- GEMM2: 128x128 tile, full K=3072, non-atomic eo output ----------------
__global__ __launch_bounds__(256) void gemm2_kernel(
    const u16* __restrict__ h,      // [NROWS][H]
    const u16* __restrict__ w2t,    // [E][C][H]
    const int* __restrict__ tile_e, const int* __restrict__ tile_rs,
    const int* __restrict__ tile_nrows,
    u16* __restrict__ eo)           // [NROWS][C] bf16 expert outputs (prob pre-folded)
{
    const int bt = blockIdx.x;
    const int rows = tile_nrows[bt];
    if (rows == 0) return;
    const int e = tile_e[bt];
    const int row_start = tile_rs[bt];
    const int jn = blockIdx.y;      // C col tile (0..5)

    __shared__ u16 As[128 * 64];
    __shared__ u16 Bs[128 * 64];

    const int tid = threadIdx.x;
    const int lane = tid & 63;
    const int wave = tid >> 6;
    const int wm = wave & 1, wn = wave >> 1;
    const int m_in = lane & 15, quad = lane >> 4;

    const u16* a_src[4];
    const u16* b_src[4];
#pragma unroll
    for (int it = 0; it < 4; ++it) {
        int idx = it * 256 + tid;
        int r = idx >> 3;
        int colel = (((idx & 7) ^ (r & 7)) * 8);
        int ar = (r < rows) ? r : 0;
        a_src[it] = h + (size_t)(row_start + ar) * H_DIM + colel;
        b_src[it] = w2t + ((size_t)e * C_DIM + jn * 128 + r) * H_DIM + colel;
    }

    const int sw0 = ((quad)     ^ (m_in & 7)) * 8;
    const int sw1 = ((4 + quad) ^ (m_in & 7)) * 8;

    f32x4 acc[4][4];
#pragma unroll
    for (int i = 0; i < 4; ++i)
#pragma unroll
        for (int j = 0; j < 4; ++j) acc[i][j] = (f32x4){0.f, 0.f, 0.f, 0.f};

    for (int k0 = 0; k0 < H_DIM; k0 += 64) {
#pragma unroll
        for (int it = 0; it < 4; ++it) {
            async_copy16(&As[(it * 256 + tid) * 8], a_src[it] + k0);
            async_copy16(&Bs[(it * 256 + tid) * 8], b_src[it] + k0);
        }
        __syncthreads();
#pragma unroll
        for (int ks = 0; ks < 2; ++ks) {
            const int sw = ks ? sw1 : sw0;
            bf16x8 af[4], bfr[4];
#pragma unroll
            for (int t = 0; t < 4; ++t)
                af[t] = __builtin_bit_cast(bf16x8,
                    *(const short8*)&As[(wm * 64 + t * 16 + m_in) * 64 + sw]);
#pragma unroll
            for (int t = 0; t < 4; ++t)
                bfr[t] = __builtin_bit_cast(bf16x8,
                    *(const short8*)&Bs[(wn * 64 + t * 16 + m_in) * 64 + sw]);
#pragma unroll
            for (int i = 0; i < 4; ++i)
#pragma unroll
                for (int j = 0; j < 4; ++j)
                    acc[i][j] = __builtin_amdgcn_mfma_f32_16x16x32_bf16(af[i], bfr[j], acc[i][j], 0, 0, 0);
        }
        __syncthreads();
    }

#pragma unroll
    for (int i = 0; i < 4; ++i) {
#pragma unroll
        for (int r = 0; r < 4; ++r) {
            int lrow = wm * 64 + i * 16 + quad * 4 + r;
            if (lrow < rows) {
                u16* orow = eo + (size_t)(row_start + lrow) * C_DIM + jn * 128;
#pragma unroll
                for (int j = 0; j < 4; ++j)
                    orow[wn * 64 + j * 16 + m_in] = f2bf(acc[i][j][r]);
            }
        }
    }
}

// ---------------- combine: out[t] = eo[r0] + eo[r1] + p0*b2[e0] + p1*b2[e1] ----------------
__global__ void combine_kernel(const u16* __restrict__ eo, const int* __restrict__ tok2row,
                               const int* __restrict__ topk_idx, const float* __restrict__ topk_prob,
                               const float* __restrict__ b2, float* __restrict__ out) {
    int t = blockIdx.x;
    int r0 = tok2row[t * 2], r1 = tok2row[t * 2 + 1];
    int e0 = topk_idx[t * 2], e1 = topk_idx[t * 2 + 1];
    float p0 = topk_prob[t * 2], p1 = topk_prob[t * 2 + 1];
    const u16* a = eo + (size_t)r0 * C_DIM;
    const u16* b = eo + (size_t)r1 * C_DIM;
    for (int c = threadIdx.x; c < C_DIM; c += blockDim.x)
        out[(size_t)t * C_DIM + c] =
            bf2f(a[c]) + bf2f(b[c]) + p0 * b2[e0 * C_DIM + c] + p1 * b2[e1 * C_DIM + c];
}

// ---------------- launch ----------------
extern "C" void kernel_launch(void* const* d_in, const int* in_sizes, int n_in,
                              void* d_out, int out_size, void* d_ws, size_t ws_size,
                              hipStream_t stream) {
    const float* x      = (const float*)d_in[0];
    const float* gate_w = (const float*)d_in[1];
    const float* gate_b = (const float*)d_in[2];
    const float* w1     = (const float*)d_in[3];
    const float* b1     = (const float*)d_in[4];
    const float* w2     = (const float*)d_in[5];
    const float* b2     = (const float*)d_in[6];
    float* out = (float*)d_out;
    char* ws = (char*)d_ws;

    // ---- workspace layout ----
    int*   t1_e       = (int*)(ws + 0);
    int*   t1_rs      = (int*)(ws + 512);
    int*   t1_rows    = (int*)(ws + 1024);
    int*   t2_e       = (int*)(ws + 1536);
    int*   t2_rs      = (int*)(ws + 2240);
    int*   t2_rows    = (int*)(ws + 2944);
    int*   topk_idx   = (int*)(ws + 4096);
    float* topk_prob  = (float*)(ws + 4096 + 65536);
    int*   row_token  = (int*)(ws + 4096 + 2 * 65536);
    float* row_prob   = (float*)(ws + 4096 + 3 * 65536);
    int*   tok2row    = (int*)(ws + 4096 + 4 * 65536);
    int*   block_hist = (int*)(ws + 4096 + 5 * 65536);
    int*   block_base = (int*)(ws + 4096 + 5 * 65536 + 2048);
    size_t off = 1 << 20;
    u16* xb  = (u16*)(ws + off);  off += (size_t)N_TOK * C_DIM * 2;          // 12.6 MB
    u16* w1t = (u16*)(ws + off);  off += (size_t)E_NUM * C_DIM * H_DIM * 2;  // 37.7 MB
    u16* w2t = (u16*)(ws + off);  off += (size_t)E_NUM * C_DIM * H_DIM * 2;  // 37.7 MB
    u16* hbuf= (u16*)(ws + off);                                             // 100.7 MB
    // eo overlaps xb (+ head of w1t): both are dead once gemm1 completes, and
    // gemm2/combine are stream-ordered after gemm1.
    u16* eo  = (u16*)(ws + (1 << 20));                                       // 25.2 MB

    cast_x_kernel<<<(N_TOK * C_DIM) / 1024, 256, 0, stream>>>(x, xb);
    transpose_cast_kernel<<<dim3(H_DIM / 32, C_DIM / 32, E_NUM), dim3(32, 8), 0, stream>>>(w1, w1t, C_DIM, H_DIM);
    transpose_cast_kernel<<<dim3(C_DIM / 32, H_DIM / 32, E_NUM), dim3(32, 8), 0, stream>>>(w2, w2t, H_DIM, C_DIM);
    gating_kernel<<<N_TOK, 64, 0, stream>>>(x, gate_w, gate_b, topk_idx, topk_prob);
    hist_kernel<<<NBLK, 256, 0, stream>>>(topk_idx, block_hist);
    scan_tables_kernel<<<1, 1, 0, stream>>>(block_hist, t1_e, t1_rs, t1_rows, t2_e, t2_rs, t2_rows, block_base);
    scatter_kernel<<<NBLK, 256, 0, stream>>>(topk_idx, topk_prob, block_base, row_token, row_prob, tok2row);
    gemm1_kernel<<<dim3(MAXT1, H_DIM / 128), 512, 0, stream>>>(xb, w1t, b1, t1_e, t1_rs, t1_rows,
                                                               row_token, row_prob, hbuf);
    gemm2_kernel<<<dim3(MAXT2, C_DIM / 128), 256, 0, stream>>>(hbuf, w2t, t2_e, t2_rs, t2_rows, eo);
    combine_kernel<<<N_TOK, 256, 0, stream>>>(eo, tok2row, topk_idx, topk_prob, b2, out);
}

// Round 4
// 509.180 us; speedup vs baseline: 1.7160x; 1.0747x over previous
//
#include <hip/hip_runtime.h>
#include <hip/hip_bf16.h>
#include <math.h>

// ---------------- problem constants ----------------
#define N_TOK 8192          // B*T
#define C_DIM 768
#define E_NUM 8
#define H_DIM 3072
#define NROWS (N_TOK * 2)   // token-expert pairs = 16384
#define MAXT1 72            // gemm1 row tiles of 256: 16384/256 + 8
#define MAXT2 136           // gemm2 row tiles of 128: 16384/128 + 8
#define NBLK  64            // routing blocks (NROWS/256)

typedef unsigned short u16;
typedef __attribute__((ext_vector_type(8))) short   short8;
typedef __attribute__((ext_vector_type(8))) __bf16  bf16x8;
typedef __attribute__((ext_vector_type(4))) float   f32x4;

__device__ __forceinline__ u16 f2bf(float f) {
    __hip_bfloat16 b = __float2bfloat16(f);
    return __builtin_bit_cast(u16, b);
}
__device__ __forceinline__ float bf2f(u16 u) {
    unsigned int v = ((unsigned int)u) << 16;
    return __builtin_bit_cast(float, v);
}

// tanh-form gelu: max |diff vs exact| ~3e-4, attenuated to ~3e-4 on the output
// through the W2 reduction — far under the bf16 storage noise. ~10 VALU ops
// (1 transcendental) vs erff's ~30+.
__device__ __forceinline__ float gelu_fast(float x) {
    float x2 = x * x;
    float u  = x * (0.7978845608f + 0.0356774081f * x2);
    float e  = __builtin_amdgcn_exp2f(u * 2.885390082f);     // e^(2u)
    float t  = 1.f - 2.f * __builtin_amdgcn_rcpf(e + 1.f);   // tanh(u)
    return 0.5f * x * (1.f + t);
}

// async global->LDS DMA, 16B per lane; LDS dest is wave-uniform base + lane*16
__device__ __forceinline__ void async_copy16(void* lds, const void* g) {
    __builtin_amdgcn_global_load_lds(
        (const __attribute__((address_space(1))) void*)g,
        (__attribute__((address_space(3))) void*)lds, 16, 0, 0);
}

// ---------------- gating: 1 wave per token (no atomics) ----------------
__global__ void gating_kernel(const float* __restrict__ x, const float* __restrict__ gw,
                              const float* __restrict__ gb,
                              int* __restrict__ topk_idx, float* __restrict__ topk_prob) {
    int token = blockIdx.x;
    int lane  = threadIdx.x;
    const float* xr = x + (size_t)token * C_DIM;
    float acc[E_NUM];
#pragma unroll
    for (int e = 0; e < E_NUM; ++e) acc[e] = 0.f;
    for (int c = lane; c < C_DIM; c += 64) {
        float xv = xr[c];
#pragma unroll
        for (int e = 0; e < E_NUM; ++e) acc[e] += xv * gw[c * E_NUM + e];
    }
#pragma unroll
    for (int e = 0; e < E_NUM; ++e) {
        float v = acc[e];
        for (int off = 32; off > 0; off >>= 1) v += __shfl_down(v, off);
        acc[e] = v;
    }
    if (lane == 0) {
        float l[E_NUM];
#pragma unroll
        for (int e = 0; e < E_NUM; ++e) l[e] = acc[e] + gb[e];
        int e0 = 0;
#pragma unroll
        for (int e = 1; e < E_NUM; ++e) if (l[e] > l[e0]) e0 = e;   // first-index ties like lax.top_k
        int e1 = -1;
#pragma unroll
        for (int e = 0; e < E_NUM; ++e) if (e != e0 && (e1 < 0 || l[e] > l[e1])) e1 = e;
        // renormalized top-2 softmax == 2-way softmax of the winning logits
        float p0 = 1.f / (1.f + expf(l[e1] - l[e0]));
        topk_idx[token * 2]      = e0;
        topk_idx[token * 2 + 1]  = e1;
        topk_prob[token * 2]     = p0;
        topk_prob[token * 2 + 1] = 1.f - p0;
    }
}

// ---------------- routing: ballot histogram -> scan -> rank scatter (atomic-free) ----------------
__global__ void hist_kernel(const int* __restrict__ topk_idx, int* __restrict__ block_hist) {
    __shared__ int cnt[E_NUM];
    int tid = threadIdx.x;
    if (tid < E_NUM) cnt[tid] = 0;
    __syncthreads();
    int e = topk_idx[blockIdx.x * 256 + tid];
    int lane = tid & 63;
#pragma unroll
    for (int E = 0; E < E_NUM; ++E) {
        unsigned long long m = __ballot(e == E);
        if (lane == 0) atomicAdd(&cnt[E], __popcll(m));   // LDS atomic, 4 waves only
    }
    __syncthreads();
    if (tid < E_NUM) block_hist[blockIdx.x * E_NUM + tid] = cnt[tid];
}

__global__ void scan_tables_kernel(const int* __restrict__ block_hist,
                                   int* __restrict__ t1_e, int* __restrict__ t1_rs, int* __restrict__ t1_rows,
                                   int* __restrict__ t2_e, int* __restrict__ t2_rs, int* __restrict__ t2_rows,
                                   int* __restrict__ block_base) {
    if (threadIdx.x || blockIdx.x) return;
    int counts[E_NUM], offsets[E_NUM];
    for (int e = 0; e < E_NUM; ++e) {
        int s = 0;
        for (int b = 0; b < NBLK; ++b) s += block_hist[b * E_NUM + e];
        counts[e] = s;
    }
    int off = 0;
    for (int e = 0; e < E_NUM; ++e) { offsets[e] = off; off += counts[e]; }
    for (int e = 0; e < E_NUM; ++e) {
        int s = offsets[e];
        for (int b = 0; b < NBLK; ++b) { block_base[b * E_NUM + e] = s; s += block_hist[b * E_NUM + e]; }
    }
    // 256-row tiles for gemm1
    int t = 0;
    for (int e = 0; e < E_NUM; ++e)
        for (int j = 0; j < counts[e]; j += 256) {
            t1_e[t] = e; t1_rs[t] = offsets[e] + j;
            t1_rows[t] = (counts[e] - j < 256) ? (counts[e] - j) : 256;
            ++t;
        }
    for (; t < MAXT1; ++t) { t1_e[t] = 0; t1_rs[t] = 0; t1_rows[t] = 0; }
    // 128-row tiles for gemm2
    t = 0;
    for (int e = 0; e < E_NUM; ++e)
        for (int j = 0; j < counts[e]; j += 128) {
            t2_e[t] = e; t2_rs[t] = offsets[e] + j;
            t2_rows[t] = (counts[e] - j < 128) ? (counts[e] - j) : 128;
            ++t;
        }
    for (; t < MAXT2; ++t) { t2_e[t] = 0; t2_rs[t] = 0; t2_rows[t] = 0; }
}

__global__ void scatter_kernel(const int* __restrict__ topk_idx, const float* __restrict__ topk_prob,
                               const int* __restrict__ block_base,
                               int* __restrict__ row_token, float* __restrict__ row_prob,
                               int* __restrict__ tok2row) {
    __shared__ int wcount[4][E_NUM];
    __shared__ int wbase[4][E_NUM];
    int tid = threadIdx.x, lane = tid & 63, wave = tid >> 6;
    int idx = blockIdx.x * 256 + tid;
    int e = topk_idx[idx];
    float p = topk_prob[idx];
    int rank = 0;
    unsigned long long lt = (1ull << lane) - 1ull;
#pragma unroll
    for (int E = 0; E < E_NUM; ++E) {
        unsigned long long m = __ballot(e == E);
        if (lane == 0) wcount[wave][E] = __popcll(m);
        if (e == E) rank = __popcll(m & lt);
    }
    __syncthreads();
    if (tid < E_NUM) {
        int s = 0;
#pragma unroll
        for (int w = 0; w < 4; ++w) { wbase[w][tid] = s; s += wcount[w][tid]; }
    }
    __syncthreads();
    int pos = block_base[blockIdx.x * E_NUM + e] + wbase[wave][e] + rank;
    row_token[pos] = idx >> 1;
    row_prob[pos]  = p;
    tok2row[idx]   = pos;
}

// ---------------- casts ----------------
__global__ void cast_x_kernel(const float* __restrict__ x, u16* __restrict__ xb) {
    int i = (blockIdx.x * blockDim.x + threadIdx.x) * 4;
    float4 v = *(const float4*)(x + i);
    u16 p[4] = {f2bf(v.x), f2bf(v.y), f2bf(v.z), f2bf(v.w)};
    *(unsigned long long*)(xb + i) = *(unsigned long long*)p;
}

// in: [E][R][C] fp32 -> out: [E][C][R] bf16.  64x64 tile, 256 threads,
// float4 loads / 8B stores; LDS access is exactly 2-way (free on CDNA4).
__global__ void transpose_cast_kernel(const float* __restrict__ in, u16* __restrict__ out,
                                      int R, int C) {
    __shared__ float tile[64][65];
    size_t mat = (size_t)R * C;
    const float* src = in + blockIdx.z * mat;
    u16* dst = out + blockIdx.z * mat;
    int c0 = blockIdx.x * 64, r0 = blockIdx.y * 64;
    int tx = threadIdx.x & 15, ty = threadIdx.x >> 4;   // 16 x 16
#pragma unroll
    for (int k = 0; k < 4; ++k) {
        float4 v = *(const float4*)(src + (size_t)(r0 + ty + 16 * k) * C + c0 + tx * 4);
        tile[ty + 16 * k][tx * 4 + 0] = v.x;
        tile[ty + 16 * k][tx * 4 + 1] = v.y;
        tile[ty + 16 * k][tx * 4 + 2] = v.z;
        tile[ty + 16 * k][tx * 4 + 3] = v.w;
    }
    __syncthreads();
#pragma unroll
    for (int k = 0; k < 4; ++k) {
        int c = ty + 16 * k;
        u16 p[4];
#pragma unroll
        for (int j = 0; j < 4; ++j) p[j] = f2bf(tile[tx * 4 + j][c]);
        *(unsigned long long*)(dst + (size_t)(c0 + c) * R + r0 + tx * 4) =
            *(unsigned long long*)p;
    }
}

// ============ GEMM cores: BK=64, 16x16x32 bf16 MFMA, XOR-swizzled LDS ============
// Swizzle: logical 16B unit u of row r lives at physical unit u^(r&7); DMA writes
// physical-contiguous (base+lane*16), lanes fetch the swizzled global column.

// ---------------- GEMM1: 256x128 tile, 8 waves ----------------
// h[r,:] = row_prob[r] * gelu(Xg[r,:] @ W1[e] + b1[e])
__global__ __launch_bounds__(512) void gemm1_kernel(
    const u16* __restrict__ xb,     // [N_TOK][C]
    const u16* __restrict__ w1t,    // [E][H][C]
    const float* __restrict__ b1,   // [E][H]
    const int* __restrict__ tile_e, const int* __restrict__ tile_rs,
    const int* __restrict__ tile_nrows,
    const int* __restrict__ row_token, const float* __restrict__ row_prob,
    u16* __restrict__ h)            // [NROWS][H]
{
    const int bt = blockIdx.x;
    const int rows = tile_nrows[bt];
    if (rows == 0) return;
    const int e = tile_e[bt];
    const int row_start = tile_rs[bt];
    const int jn = blockIdx.y;      // H col tile (0..23)

    __shared__ u16 As[256 * 64];    // 32 KB
    __shared__ u16 Bs[128 * 64];    // 16 KB

    const int tid = threadIdx.x;
    const int lane = tid & 63;
    const int wave = tid >> 6;
    const int wm = wave & 3, wn = wave >> 2;   // 4 m-subtiles x 2 n-subtiles of 64
    const int m_in = lane & 15, quad = lane >> 4;

    const u16* a_src[8];
    const u16* b_src[2];
#pragma unroll
    for (int it = 0; it < 8; ++it) {
        int idx = it * 512 + tid;                 // 0..4095 covers 256 rows x 64 cols /8
        int r = idx >> 3;
        int colel = (((idx & 7) ^ (r & 7)) * 8);  // swizzled source column
        int tok = row_token[row_start + ((r < rows) ? r : 0)];
        a_src[it] = xb + (size_t)tok * C_DIM + colel;
    }
#pragma unroll
    for (int it = 0; it < 2; ++it) {
        int idx = it * 512 + tid;                 // 0..1023 covers 128 rows x 64 cols /8
        int r = idx >> 3;
        int colel = (((idx & 7) ^ (r & 7)) * 8);
        b_src[it] = w1t + ((size_t)e * H_DIM + jn * 128 + r) * C_DIM + colel;
    }

    const int sw0 = ((quad)     ^ (m_in & 7)) * 8;
    const int sw1 = ((4 + quad) ^ (m_in & 7)) * 8;

    f32x4 acc[4][4];
#pragma unroll
    for (int i = 0; i < 4; ++i)
#pragma unroll
        for (int j = 0; j < 4; ++j) acc[i][j] = (f32x4){0.f, 0.f, 0.f, 0.f};

    for (int k0 = 0; k0 < C_DIM; k0 += 64) {
#pragma unroll
        for (int it = 0; it < 8; ++it)
            async_copy16(&As[(it * 512 + tid) * 8], a_src[it] + k0);
#pragma unroll
        for (int it = 0; it < 2; ++it)
            async_copy16(&Bs[(it * 512 + tid) * 8], b_src[it] + k0);
        __syncthreads();
#pragma unroll
        for (int ks = 0; ks < 2; ++ks) {
            const int sw = ks ? sw1 : sw0;
            bf16x8 af[4], bfr[4];
#pragma unroll
            for (int t = 0; t < 4; ++t)
                af[t] = __builtin_bit_cast(bf16x8,
                    *(const short8*)&As[(wm * 64 + t * 16 + m_in) * 64 + sw]);
#pragma unroll
            for (int t = 0; t < 4; ++t)
                bfr[t] = __builtin_bit_cast(bf16x8,
                    *(const short8*)&Bs[(wn * 64 + t * 16 + m_in) * 64 + sw]);
#pragma unroll
            for (int i = 0; i < 4; ++i)
#pragma unroll
                for (int j = 0; j < 4; ++j)
                    acc[i][j] = __builtin_amdgcn_mfma_f32_16x16x32_bf16(af[i], bfr[j], acc[i][j], 0, 0, 0);
        }
        __syncthreads();
    }

    const float* b1e = b1 + e * H_DIM + jn * 128;
#pragma unroll
    for (int i = 0; i < 4; ++i) {
#pragma unroll
        for (int r = 0; r < 4; ++r) {
            int lrow = wm * 64 + i * 16 + quad * 4 + r;
            if (lrow < rows) {
                int grow = row_start + lrow;
                float p = row_prob[grow];
#pragma unroll
                for (int j = 0; j < 4; ++j) {
                    int lcol = wn * 64 + j * 16 + m_in;
                    float v = acc[i][j][r] + b1e[lcol];
                    h[(size_t)grow * H_DIM + jn * 128 + lcol] = f2bf(gelu_fast(v) * p);
                }
            }
        }
    }
}

// ---------------- GEMM2: 128x128 tile, split-K=2, bf16 partials ----------------
#define KSPLIT 2
#define KCHUNK (H_DIM / KSPLIT)   // 1536

__global__ __launch_bounds__(256) void gemm2_kernel(
    const u16* __restrict__ h,      // [NROWS][H]
    const u16* __restrict__ w2t,    // [E][C][H]
    const int* __restrict__ tile_e, const int* __restrict__ tile_rs,
    const int* __restrict__ tile_nrows,
    u16* __restrict__ eo)           // [KSPLIT][NROWS][C] bf16 partials
{
    const int bt = blockIdx.x;
    const int rows = tile_nrows[bt];
    if (rows == 0) return;
    const int e = tile_e[bt];
    const int row_start = tile_rs[bt];
    const int jn = blockIdx.y;      // C col tile (0..5)
    const int kz = blockIdx.z;      // K split

    __shared__ u16 As[128 * 64];
    __shared__ u16 Bs[128 * 64];

    const int tid = threadIdx.x;
    const int lane = tid & 63;
    const int wave = tid >> 6;
    const int wm = wave & 1, wn = wave >> 1;
    const int m_in = lane & 15, quad = lane >> 4;

    const u16* a_src[4];
    const u16* b_src[4];
#pragma unroll
    for (int it = 0; it < 4; ++it) {
        int idx = it * 256 + tid;
        int r = idx >> 3;
        int colel = (((idx & 7) ^ (r & 7)) * 8);
        int ar = (r < rows) ? r : 0;
        a_src[it] = h + (size_t)(row_start + ar) * H_DIM + colel;
        b_src[it] = w2t + ((size_t)e * C_DIM + jn * 128 + r) * H_DIM + colel;
    }

    const int sw0 = ((quad)     ^ (m_in & 7)) * 8;
    const int sw1 = ((4 + quad) ^ (m_in & 7)) * 8;

    f32x4 acc[4][4];
#pragma unroll
    for (int i = 0; i < 4; ++i)
#pragma unroll
        for (int j = 0; j < 4; ++j) acc[i][j] = (f32x4){0.f, 0.f, 0.f, 0.f};

    for (int k0 = kz * KCHUNK; k0 < (kz + 1) * KCHUNK; k0 += 64) {
#pragma unroll
        for (int it = 0; it < 4; ++it) {
            async_copy16(&As[(it * 256 + tid) * 8], a_src[it] + k0);
            async_copy16(&Bs[(it * 256 + tid) * 8], b_src[it] + k0);
        }
        __syncthreads();
#pragma unroll
        for (int ks = 0; ks < 2; ++ks) {
            const int sw = ks ? sw1 : sw0;
            bf16x8 af[4], bfr[4];
#pragma unroll
            for (int t = 0; t < 4; ++t)
                af[t] = __builtin_bit_cast(bf16x8,
                    *(const short8*)&As[(wm * 64 + t * 16 + m_in) * 64 + sw]);
#pragma unroll
            for (int t = 0; t < 4; ++t)
                bfr[t] = __builtin_bit_cast(bf16x8,
                    *(const short8*)&Bs[(wn * 64 + t * 16 + m_in) * 64 + sw]);
#pragma unroll
            for (int i = 0; i < 4; ++i)
#pragma unroll
                for (int j = 0; j < 4; ++j)
                    acc[i][j] = __builtin_amdgcn_mfma_f32_16x16x32_bf16(af[i], bfr[j], acc[i][j], 0, 0, 0);
        }
        __syncthreads();
    }

    u16* eop = eo + (size_t)kz * NROWS * C_DIM;
#pragma unroll
    for (int i = 0; i < 4; ++i) {
#pragma unroll
        for (int r = 0; r < 4; ++r) {
            int lrow = wm * 64 + i * 16 + quad * 4 + r;
            if (lrow < rows) {
                u16* orow = eop + (size_t)(row_start + lrow) * C_DIM + jn * 128;
#pragma unroll
                for (int j = 0; j < 4; ++j)
                    orow[wn * 64 + j * 16 + m_in] = f2bf(acc[i][j][r]);
            }
        }
    }
}

// ---------------- combine: out[t] = sum of 4 partial rows + weighted biases ----------------
__global__ void combine_kernel(const u16* __restrict__ eo, const int* __restrict__ tok2row,
                               const int* __restrict__ topk_idx, const float* __restrict__ topk_prob,
                               const float* __restrict__ b2, float* __restrict__ out) {
    int t = blockIdx.x;
    int c = threadIdx.x * 4;                      // 192 threads x 4 floats = 768
    int r0 = tok2row[t * 2], r1 = tok2row[t * 2 + 1];
    int e0 = topk_idx[t * 2], e1 = topk_idx[t * 2 + 1];
    float p0 = topk_prob[t * 2], p1 = topk_prob[t * 2 + 1];
    const u16* a0 = eo + (size_t)r0 * C_DIM + c;
    const u16* a1 = eo + (size_t)NROWS * C_DIM + (size_t)r0 * C_DIM + c;
    const u16* b0 = eo + (size_t)r1 * C_DIM + c;
    const u16* b1 = eo + (size_t)NROWS * C_DIM + (size_t)r1 * C_DIM + c;
    ushort4 va0 = *(const ushort4*)a0, va1 = *(const ushort4*)a1;
    ushort4 vb0 = *(const ushort4*)b0, vb1 = *(const ushort4*)b1;
    float4 g0 = *(const float4*)(b2 + e0 * C_DIM + c);
    float4 g1 = *(const float4*)(b2 + e1 * C_DIM + c);
    float4 o;
    o.x = bf2f(va0.x) + bf2f(va1.x) + bf2f(vb0.x) + bf2f(vb1.x) + p0 * g0.x + p1 * g1.x;
    o.y = bf2f(va0.y) + bf2f(va1.y) + bf2f(vb0.y) + bf2f(vb1.y) + p0 * g0.y + p1 * g1.y;
    o.z = bf2f(va0.z) + bf2f(va1.z) + bf2f(vb0.z) + bf2f(vb1.z) + p0 * g0.z + p1 * g1.z;
    o.w = bf2f(va0.w) + bf2f(va1.w) + bf2f(vb0.w) + bf2f(vb1.w) + p0 * g0.w + p1 * g1.w;
    *(float4*)(out + (size_t)t * C_DIM + c) = o;
}

// ---------------- launch ----------------
extern "C" void kernel_launch(void* const* d_in, const int* in_sizes, int n_in,
                              void* d_out, int out_size, void* d_ws, size_t ws_size,
                              hipStream_t stream) {
    const float* x      = (const float*)d_in[0];
    const float* gate_w = (const float*)d_in[1];
    const float* gate_b = (const float*)d_in[2];
    const float* w1     = (const float*)d_in[3];
    const float* b1     = (const float*)d_in[4];
    const float* w2     = (const float*)d_in[5];
    const float* b2     = (const float*)d_in[6];
    float* out = (float*)d_out;
    char* ws = (char*)d_ws;

    // ---- workspace layout (~181 MB) ----
    int*   t1_e       = (int*)(ws + 0);
    int*   t1_rs      = (int*)(ws + 512);
    int*   t1_rows    = (int*)(ws + 1024);
    int*   t2_e       = (int*)(ws + 1536);
    int*   t2_rs      = (int*)(ws + 2240);
    int*   t2_rows    = (int*)(ws + 2944);
    int*   topk_idx   = (int*)(ws + 4096);
    float* topk_prob  = (float*)(ws + 4096 + 65536);
    int*   row_token  = (int*)(ws + 4096 + 2 * 65536);
    float* row_prob   = (float*)(ws + 4096 + 3 * 65536);
    int*   tok2row    = (int*)(ws + 4096 + 4 * 65536);
    int*   block_hist = (int*)(ws + 4096 + 5 * 65536);
    int*   block_base = (int*)(ws + 4096 + 5 * 65536 + 2048);
    size_t off = 1 << 20;
    u16* xb  = (u16*)(ws + off);  off += (size_t)N_TOK * C_DIM * 2;          // 12.6 MB
    u16* w1t = (u16*)(ws + off);  off += (size_t)E_NUM * C_DIM * H_DIM * 2;  // 37.7 MB
    u16* w2t = (u16*)(ws + off);  off += (size_t)E_NUM * C_DIM * H_DIM * 2;  // 37.7 MB
    u16* hbuf= (u16*)(ws + off);                                             // 100.7 MB
    // eo partials [KSPLIT][NROWS][C] bf16 = 50.33 MB: overlays xb+w1t, which are
    // dead once gemm1 completes (gemm2/combine are stream-ordered after it).
    u16* eo  = (u16*)(ws + (1 << 20));

    cast_x_kernel<<<(N_TOK * C_DIM) / 1024, 256, 0, stream>>>(x, xb);
    transpose_cast_kernel<<<dim3(H_DIM / 64, C_DIM / 64, E_NUM), 256, 0, stream>>>(w1, w1t, C_DIM, H_DIM);
    transpose_cast_kernel<<<dim3(C_DIM / 64, H_DIM / 64, E_NUM), 256, 0, stream>>>(w2, w2t, H_DIM, C_DIM);
    gating_kernel<<<N_TOK, 64, 0, stream>>>(x, gate_w, gate_b, topk_idx, topk_prob);
    hist_kernel<<<NBLK, 256, 0, stream>>>(topk_idx, block_hist);
    scan_tables_kernel<<<1, 1, 0, stream>>>(block_hist, t1_e, t1_rs, t1_rows, t2_e, t2_rs, t2_rows, block_base);
    scatter_kernel<<<NBLK, 256, 0, stream>>>(topk_idx, topk_prob, block_base, row_token, row_prob, tok2row);
    gemm1_kernel<<<dim3(MAXT1, H_DIM / 128), 512, 0, stream>>>(xb, w1t, b1, t1_e, t1_rs, t1_rows,
                                                               row_token, row_prob, hbuf);
    gemm2_kernel<<<dim3(MAXT2, C_DIM / 128, KSPLIT), 256, 0, stream>>>(hbuf, w2t, t2_e, t2_rs, t2_rows, eo);
    combine_kernel<<<N_TOK, 192, 0, stream>>>(eo, tok2row, topk_idx, topk_prob, b2, out);
}

// Round 5
// 463.966 us; speedup vs baseline: 1.8832x; 1.0975x over previous
//
#include <hip/hip_runtime.h>
#include <hip/hip_bf16.h>
#include <math.h>

// ---------------- problem constants ----------------
#define N_TOK 8192          // B*T
#define C_DIM 768
#define E_NUM 8
#define H_DIM 3072
#define NROWS (N_TOK * 2)   // token-expert pairs = 16384
#define MAXT1 72            // row tiles of 256: 16384/256 + 8
#define NBLK  64            // routing blocks (NROWS/256)
#define JN1   24            // gemm1 H col tiles (3072/128)
#define KSPLIT 2
#define KCHUNK (H_DIM / KSPLIT)   // 1536

typedef unsigned short u16;
typedef __attribute__((ext_vector_type(8))) short   short8;
typedef __attribute__((ext_vector_type(8))) __bf16  bf16x8;
typedef __attribute__((ext_vector_type(4))) float   f32x4;

__device__ __forceinline__ u16 f2bf(float f) {
    __hip_bfloat16 b = __float2bfloat16(f);
    return __builtin_bit_cast(u16, b);
}
__device__ __forceinline__ float bf2f(u16 u) {
    unsigned int v = ((unsigned int)u) << 16;
    return __builtin_bit_cast(float, v);
}

// tanh-form gelu (~3e-4 max dev vs exact, invisible under bf16 noise)
__device__ __forceinline__ float gelu_fast(float x) {
    float x2 = x * x;
    float u  = x * (0.7978845608f + 0.0356774081f * x2);
    float e  = __builtin_amdgcn_exp2f(u * 2.885390082f);     // e^(2u)
    float t  = 1.f - 2.f * __builtin_amdgcn_rcpf(e + 1.f);   // tanh(u)
    return 0.5f * x * (1.f + t);
}

// async global->LDS DMA, 16B per lane; LDS dest is wave-uniform base + lane*16
__device__ __forceinline__ void async_copy16(void* lds, const void* g) {
    __builtin_amdgcn_global_load_lds(
        (const __attribute__((address_space(1))) void*)g,
        (__attribute__((address_space(3))) void*)lds, 16, 0, 0);
}

// ---------------- gating + x cast fused: 1 wave per token ----------------
__global__ void gating_kernel(const float* __restrict__ x, const float* __restrict__ gw,
                              const float* __restrict__ gb,
                              int* __restrict__ topk_idx, float* __restrict__ topk_prob,
                              u16* __restrict__ xb) {
    int token = blockIdx.x;
    int lane  = threadIdx.x;
    const float* xr = x + (size_t)token * C_DIM;
    u16* xbr = xb + (size_t)token * C_DIM;
    float acc[E_NUM];
#pragma unroll
    for (int e = 0; e < E_NUM; ++e) acc[e] = 0.f;
    for (int c = lane; c < C_DIM; c += 64) {
        float xv = xr[c];
        xbr[c] = f2bf(xv);
#pragma unroll
        for (int e = 0; e < E_NUM; ++e) acc[e] += xv * gw[c * E_NUM + e];
    }
#pragma unroll
    for (int e = 0; e < E_NUM; ++e) {
        float v = acc[e];
        for (int off = 32; off > 0; off >>= 1) v += __shfl_down(v, off);
        acc[e] = v;
    }
    if (lane == 0) {
        float l[E_NUM];
#pragma unroll
        for (int e = 0; e < E_NUM; ++e) l[e] = acc[e] + gb[e];
        int e0 = 0;
#pragma unroll
        for (int e = 1; e < E_NUM; ++e) if (l[e] > l[e0]) e0 = e;   // first-index ties like lax.top_k
        int e1 = -1;
#pragma unroll
        for (int e = 0; e < E_NUM; ++e) if (e != e0 && (e1 < 0 || l[e] > l[e1])) e1 = e;
        float p0 = 1.f / (1.f + expf(l[e1] - l[e0]));
        topk_idx[token * 2]      = e0;
        topk_idx[token * 2 + 1]  = e1;
        topk_prob[token * 2]     = p0;
        topk_prob[token * 2 + 1] = 1.f - p0;
    }
}

// ---------------- routing: ballot histogram -> scan -> rank scatter ----------------
__global__ void hist_kernel(const int* __restrict__ topk_idx, int* __restrict__ block_hist) {
    __shared__ int cnt[E_NUM];
    int tid = threadIdx.x;
    if (tid < E_NUM) cnt[tid] = 0;
    __syncthreads();
    int e = topk_idx[blockIdx.x * 256 + tid];
    int lane = tid & 63;
#pragma unroll
    for (int E = 0; E < E_NUM; ++E) {
        unsigned long long m = __ballot(e == E);
        if (lane == 0) atomicAdd(&cnt[E], __popcll(m));   // LDS atomic, 4 waves only
    }
    __syncthreads();
    if (tid < E_NUM) block_hist[blockIdx.x * E_NUM + tid] = cnt[tid];
}

__global__ void scan_tables_kernel(const int* __restrict__ block_hist,
                                   int* __restrict__ t1_e, int* __restrict__ t1_rs, int* __restrict__ t1_rows,
                                   int* __restrict__ block_base) {
    if (threadIdx.x || blockIdx.x) return;
    int counts[E_NUM], offsets[E_NUM];
    for (int e = 0; e < E_NUM; ++e) {
        int s = 0;
        for (int b = 0; b < NBLK; ++b) s += block_hist[b * E_NUM + e];
        counts[e] = s;
    }
    int off = 0;
    for (int e = 0; e < E_NUM; ++e) { offsets[e] = off; off += counts[e]; }
    for (int e = 0; e < E_NUM; ++e) {
        int s = offsets[e];
        for (int b = 0; b < NBLK; ++b) { block_base[b * E_NUM + e] = s; s += block_hist[b * E_NUM + e]; }
    }
    int t = 0;
    for (int e = 0; e < E_NUM; ++e)
        for (int j = 0; j < counts[e]; j += 256) {
            t1_e[t] = e; t1_rs[t] = offsets[e] + j;
            t1_rows[t] = (counts[e] - j < 256) ? (counts[e] - j) : 256;
            ++t;
        }
    for (; t < MAXT1; ++t) { t1_e[t] = 0; t1_rs[t] = 0; t1_rows[t] = 0; }
}

__global__ void scatter_kernel(const int* __restrict__ topk_idx, const float* __restrict__ topk_prob,
                               const int* __restrict__ block_base,
                               int* __restrict__ row_token, float* __restrict__ row_prob,
                               int* __restrict__ tok2row) {
    __shared__ int wcount[4][E_NUM];
    __shared__ int wbase[4][E_NUM];
    int tid = threadIdx.x, lane = tid & 63, wave = tid >> 6;
    int idx = blockIdx.x * 256 + tid;
    int e = topk_idx[idx];
    float p = topk_prob[idx];
    int rank = 0;
    unsigned long long lt = (1ull << lane) - 1ull;
#pragma unroll
    for (int E = 0; E < E_NUM; ++E) {
        unsigned long long m = __ballot(e == E);
        if (lane == 0) wcount[wave][E] = __popcll(m);
        if (e == E) rank = __popcll(m & lt);
    }
    __syncthreads();
    if (tid < E_NUM) {
        int s = 0;
#pragma unroll
        for (int w = 0; w < 4; ++w) { wbase[w][tid] = s; s += wcount[w][tid]; }
    }
    __syncthreads();
    int pos = block_base[blockIdx.x * E_NUM + e] + wbase[wave][e] + rank;
    row_token[pos] = idx >> 1;
    row_prob[pos]  = p;
    tok2row[idx]   = pos;
}

// in: [E][R][C] fp32 -> out: [E][C][R] bf16.  64x64 tile, 256 threads.
__global__ void transpose_cast_kernel(const float* __restrict__ in, u16* __restrict__ out,
                                      int R, int C) {
    __shared__ float tile[64][65];
    size_t mat = (size_t)R * C;
    const float* src = in + blockIdx.z * mat;
    u16* dst = out + blockIdx.z * mat;
    int c0 = blockIdx.x * 64, r0 = blockIdx.y * 64;
    int tx = threadIdx.x & 15, ty = threadIdx.x >> 4;   // 16 x 16
#pragma unroll
    for (int k = 0; k < 4; ++k) {
        float4 v = *(const float4*)(src + (size_t)(r0 + ty + 16 * k) * C + c0 + tx * 4);
        tile[ty + 16 * k][tx * 4 + 0] = v.x;
        tile[ty + 16 * k][tx * 4 + 1] = v.y;
        tile[ty + 16 * k][tx * 4 + 2] = v.z;
        tile[ty + 16 * k][tx * 4 + 3] = v.w;
    }
    __syncthreads();
#pragma unroll
    for (int k = 0; k < 4; ++k) {
        int c = ty + 16 * k;
        u16 p[4];
#pragma unroll
        for (int j = 0; j < 4; ++j) p[j] = f2bf(tile[tx * 4 + j][c]);
        *(unsigned long long*)(dst + (size_t)(c0 + c) * R + r0 + tx * 4) =
            *(unsigned long long*)p;
    }
}

// ============ GEMM cores: 256x128 tile, BK=64, 8 waves, XOR-swizzled LDS ============
// A staging: 256x64 = 2048 16B-units -> 4 DMA/thread (it<4). [R4 bug: it<8 wrote
// 2x the tile, OOB-dropped past 48K — wasted half the A-staging DMAs.]
// XCD swizzle: dispatch is round-robin over 8 XCDs, so blockIdx%8 pins work
// classes to XCDs; B col-tiles are partitioned by XCD -> per-XCD L2 reuse.

// ---------------- GEMM1: h[r,:] = row_prob[r] * gelu(Xg[r,:] @ W1[e] + b1[e]) ----------------
__global__ __launch_bounds__(512) void gemm1_kernel(
    const u16* __restrict__ xb,     // [N_TOK][C]
    const u16* __restrict__ w1t,    // [E][H][C]
    const float* __restrict__ b1,   // [E][H]
    const int* __restrict__ tile_e, const int* __restrict__ tile_rs,
    const int* __restrict__ tile_nrows,
    const int* __restrict__ row_token, const float* __restrict__ row_prob,
    u16* __restrict__ h)            // [NROWS][H]
{
    // swizzle: xcd = l&7 handles jn in {x, 8+x, 16+x}; bt fastest within XCD
    const int l = blockIdx.x;
    const int xc = l & 7, s = l >> 3;     // s in [0, 216)
    const int bt = s % MAXT1;
    const int jn = (s / MAXT1) * 8 + xc;  // [0, 24)

    const int rows = tile_nrows[bt];
    if (rows == 0) return;
    const int e = tile_e[bt];
    const int row_start = tile_rs[bt];

    __shared__ u16 As[256 * 64];    // 32 KB
    __shared__ u16 Bs[128 * 64];    // 16 KB

    const int tid = threadIdx.x;
    const int lane = tid & 63;
    const int wave = tid >> 6;
    const int wm = wave & 3, wn = wave >> 2;
    const int m_in = lane & 15, quad = lane >> 4;

    const u16* a_src[4];
    const u16* b_src[2];
#pragma unroll
    for (int it = 0; it < 4; ++it) {
        int idx = it * 512 + tid;                 // 0..2047 = 256 rows x 8 units
        int r = idx >> 3;
        int colel = (((idx & 7) ^ (r & 7)) * 8);  // swizzled source column
        int tok = row_token[row_start + ((r < rows) ? r : 0)];
        a_src[it] = xb + (size_t)tok * C_DIM + colel;
    }
#pragma unroll
    for (int it = 0; it < 2; ++it) {
        int idx = it * 512 + tid;                 // 0..1023 = 128 rows x 8 units
        int r = idx >> 3;
        int colel = (((idx & 7) ^ (r & 7)) * 8);
        b_src[it] = w1t + ((size_t)e * H_DIM + jn * 128 + r) * C_DIM + colel;
    }

    const int sw0 = ((quad)     ^ (m_in & 7)) * 8;
    const int sw1 = ((4 + quad) ^ (m_in & 7)) * 8;

    f32x4 acc[4][4];
#pragma unroll
    for (int i = 0; i < 4; ++i)
#pragma unroll
        for (int j = 0; j < 4; ++j) acc[i][j] = (f32x4){0.f, 0.f, 0.f, 0.f};

    for (int k0 = 0; k0 < C_DIM; k0 += 64) {
#pragma unroll
        for (int it = 0; it < 4; ++it)
            async_copy16(&As[(it * 512 + tid) * 8], a_src[it] + k0);
#pragma unroll
        for (int it = 0; it < 2; ++it)
            async_copy16(&Bs[(it * 512 + tid) * 8], b_src[it] + k0);
        __syncthreads();
#pragma unroll
        for (int ks = 0; ks < 2; ++ks) {
            const int sw = ks ? sw1 : sw0;
            bf16x8 af[4], bfr[4];
#pragma unroll
            for (int t = 0; t < 4; ++t)
                af[t] = __builtin_bit_cast(bf16x8,
                    *(const short8*)&As[(wm * 64 + t * 16 + m_in) * 64 + sw]);
#pragma unroll
            for (int t = 0; t < 4; ++t)
                bfr[t] = __builtin_bit_cast(bf16x8,
                    *(const short8*)&Bs[(wn * 64 + t * 16 + m_in) * 64 + sw]);
#pragma unroll
            for (int i = 0; i < 4; ++i)
#pragma unroll
                for (int j = 0; j < 4; ++j)
                    acc[i][j] = __builtin_amdgcn_mfma_f32_16x16x32_bf16(af[i], bfr[j], acc[i][j], 0, 0, 0);
        }
        __syncthreads();
    }

    const float* b1e = b1 + e * H_DIM + jn * 128;
#pragma unroll
    for (int i = 0; i < 4; ++i) {
#pragma unroll
        for (int r = 0; r < 4; ++r) {
            int lrow = wm * 64 + i * 16 + quad * 4 + r;
            if (lrow < rows) {
                int grow = row_start + lrow;
                float p = row_prob[grow];
#pragma unroll
                for (int j = 0; j < 4; ++j) {
                    int lcol = wn * 64 + j * 16 + m_in;
                    float v = acc[i][j][r] + b1e[lcol];
                    h[(size_t)grow * H_DIM + jn * 128 + lcol] = f2bf(gelu_fast(v) * p);
                }
            }
        }
    }
}

// ---------------- GEMM2: 256x128 tile, split-K=2, bf16 partials ----------------
__global__ __launch_bounds__(512) void gemm2_kernel(
    const u16* __restrict__ h,      // [NROWS][H]
    const u16* __restrict__ w2t,    // [E][C][H]
    const int* __restrict__ tile_e, const int* __restrict__ tile_rs,
    const int* __restrict__ tile_nrows,
    u16* __restrict__ eo)           // [KSPLIT][NROWS][C] bf16 partials
{
    // swizzle: xcd = l&7 -> bt = xc + 8*(s/12); combo fastest (A tile reused
    // across all 12 (jn,kz) combos within one XCD's L2)
    const int l = blockIdx.x;
    const int xc = l & 7, s = l >> 3;     // s in [0, 108)
    const int combo = s % 12;
    const int bt = xc + 8 * (s / 12);     // [0, 72)
    const int jn = combo >> 1;            // [0, 6)
    const int kz = combo & 1;

    const int rows = tile_nrows[bt];
    if (rows == 0) return;
    const int e = tile_e[bt];
    const int row_start = tile_rs[bt];

    __shared__ u16 As[256 * 64];    // 32 KB
    __shared__ u16 Bs[128 * 64];    // 16 KB

    const int tid = threadIdx.x;
    const int lane = tid & 63;
    const int wave = tid >> 6;
    const int wm = wave & 3, wn = wave >> 2;
    const int m_in = lane & 15, quad = lane >> 4;

    const u16* a_src[4];
    const u16* b_src[2];
#pragma unroll
    for (int it = 0; it < 4; ++it) {
        int idx = it * 512 + tid;
        int r = idx >> 3;
        int colel = (((idx & 7) ^ (r & 7)) * 8);
        int ar = (r < rows) ? r : 0;
        a_src[it] = h + (size_t)(row_start + ar) * H_DIM + colel;
    }
#pragma unroll
    for (int it = 0; it < 2; ++it) {
        int idx = it * 512 + tid;
        int r = idx >> 3;
        int colel = (((idx & 7) ^ (r & 7)) * 8);
        b_src[it] = w2t + ((size_t)e * C_DIM + jn * 128 + r) * H_DIM + colel;
    }

    const int sw0 = ((quad)     ^ (m_in & 7)) * 8;
    const int sw1 = ((4 + quad) ^ (m_in & 7)) * 8;

    f32x4 acc[4][4];
#pragma unroll
    for (int i = 0; i < 4; ++i)
#pragma unroll
        for (int j = 0; j < 4; ++j) acc[i][j] = (f32x4){0.f, 0.f, 0.f, 0.f};

    for (int k0 = kz * KCHUNK; k0 < (kz + 1) * KCHUNK; k0 += 64) {
#pragma unroll
        for (int it = 0; it < 4; ++it)
            async_copy16(&As[(it * 512 + tid) * 8], a_src[it] + k0);
#pragma unroll
        for (int it = 0; it < 2; ++it)
            async_copy16(&Bs[(it * 512 + tid) * 8], b_src[it] + k0);
        __syncthreads();
#pragma unroll
        for (int ks = 0; ks < 2; ++ks) {
            const int sw = ks ? sw1 : sw0;
            bf16x8 af[4], bfr[4];
#pragma unroll
            for (int t = 0; t < 4; ++t)
                af[t] = __builtin_bit_cast(bf16x8,
                    *(const short8*)&As[(wm * 64 + t * 16 + m_in) * 64 + sw]);
#pragma unroll
            for (int t = 0; t < 4; ++t)
                bfr[t] = __builtin_bit_cast(bf16x8,
                    *(const short8*)&Bs[(wn * 64 + t * 16 + m_in) * 64 + sw]);
#pragma unroll
            for (int i = 0; i < 4; ++i)
#pragma unroll
                for (int j = 0; j < 4; ++j)
                    acc[i][j] = __builtin_amdgcn_mfma_f32_16x16x32_bf16(af[i], bfr[j], acc[i][j], 0, 0, 0);
        }
        __syncthreads();
    }

    u16* eop = eo + (size_t)kz * NROWS * C_DIM;
#pragma unroll
    for (int i = 0; i < 4; ++i) {
#pragma unroll
        for (int r = 0; r < 4; ++r) {
            int lrow = wm * 64 + i * 16 + quad * 4 + r;
            if (lrow < rows) {
                u16* orow = eop + (size_t)(row_start + lrow) * C_DIM + jn * 128;
#pragma unroll
                for (int j = 0; j < 4; ++j)
                    orow[wn * 64 + j * 16 + m_in] = f2bf(acc[i][j][r]);
            }
        }
    }
}

// ---------------- combine: out[t] = sum of 4 partial rows + weighted biases ----------------
__global__ void combine_kernel(const u16* __restrict__ eo, const int* __restrict__ tok2row,
                               const int* __restrict__ topk_idx, const float* __restrict__ topk_prob,
                               const float* __restrict__ b2, float* __restrict__ out) {
    int t = blockIdx.x;
    int c = threadIdx.x * 4;                      // 192 threads x 4 floats = 768
    int r0 = tok2row[t * 2], r1 = tok2row[t * 2 + 1];
    int e0 = topk_idx[t * 2], e1 = topk_idx[t * 2 + 1];
    float p0 = topk_prob[t * 2], p1 = topk_prob[t * 2 + 1];
    const u16* a0 = eo + (size_t)r0 * C_DIM + c;
    const u16* a1 = eo + (size_t)NROWS * C_DIM + (size_t)r0 * C_DIM + c;
    const u16* b0 = eo + (size_t)r1 * C_DIM + c;
    const u16* b1 = eo + (size_t)NROWS * C_DIM + (size_t)r1 * C_DIM + c;
    ushort4 va0 = *(const ushort4*)a0, va1 = *(const ushort4*)a1;
    ushort4 vb0 = *(const ushort4*)b0, vb1 = *(const ushort4*)b1;
    float4 g0 = *(const float4*)(b2 + e0 * C_DIM + c);
    float4 g1 = *(const float4*)(b2 + e1 * C_DIM + c);
    float4 o;
    o.x = bf2f(va0.x) + bf2f(va1.x) + bf2f(vb0.x) + bf2f(vb1.x) + p0 * g0.x + p1 * g1.x;
    o.y = bf2f(va0.y) + bf2f(va1.y) + bf2f(vb0.y) + bf2f(vb1.y) + p0 * g0.y + p1 * g1.y;
    o.z = bf2f(va0.z) + bf2f(va1.z) + bf2f(vb0.z) + bf2f(vb1.z) + p0 * g0.z + p1 * g1.z;
    o.w = bf2f(va0.w) + bf2f(va1.w) + bf2f(vb0.w) + bf2f(vb1.w) + p0 * g0.w + p1 * g1.w;
    *(float4*)(out + (size_t)t * C_DIM + c) = o;
}

// ---------------- launch ----------------
extern "C" void kernel_launch(void* const* d_in, const int* in_sizes, int n_in,
                              void* d_out, int out_size, void* d_ws, size_t ws_size,
                              hipStream_t stream) {
    const float* x      = (const float*)d_in[0];
    const float* gate_w = (const float*)d_in[1];
    const float* gate_b = (const float*)d_in[2];
    const float* w1     = (const float*)d_in[3];
    const float* b1     = (const float*)d_in[4];
    const float* w2     = (const float*)d_in[5];
    const float* b2     = (const float*)d_in[6];
    float* out = (float*)d_out;
    char* ws = (char*)d_ws;

    // ---- workspace layout (~189 MB) ----
    int*   t1_e       = (int*)(ws + 0);
    int*   t1_rs      = (int*)(ws + 512);
    int*   t1_rows    = (int*)(ws + 1024);
    int*   topk_idx   = (int*)(ws + 4096);
    float* topk_prob  = (float*)(ws + 4096 + 65536);
    int*   row_token  = (int*)(ws + 4096 + 2 * 65536);
    float* row_prob   = (float*)(ws + 4096 + 3 * 65536);
    int*   tok2row    = (int*)(ws + 4096 + 4 * 65536);
    int*   block_hist = (int*)(ws + 4096 + 5 * 65536);
    int*   block_base = (int*)(ws + 4096 + 5 * 65536 + 2048);
    size_t off = 1 << 20;
    u16* xb  = (u16*)(ws + off);  off += (size_t)N_TOK * C_DIM * 2;          // 12.58 MB
    u16* w1t = (u16*)(ws + off);  off += (size_t)E_NUM * C_DIM * H_DIM * 2;  // 37.75 MB
    u16* w2t = (u16*)(ws + off);  off += (size_t)E_NUM * C_DIM * H_DIM * 2;  // 37.75 MB
    u16* hbuf= (u16*)(ws + off);                                             // 100.7 MB
    // eo partials [KSPLIT=2][NROWS][C] bf16 = 50.33 MB: overlays xb+w1t exactly
    // (both dead once gemm1 completes; gemm2/combine are stream-ordered after).
    u16* eo  = (u16*)(ws + (1 << 20));

    transpose_cast_kernel<<<dim3(H_DIM / 64, C_DIM / 64, E_NUM), 256, 0, stream>>>(w1, w1t, C_DIM, H_DIM);
    transpose_cast_kernel<<<dim3(C_DIM / 64, H_DIM / 64, E_NUM), 256, 0, stream>>>(w2, w2t, H_DIM, C_DIM);
    gating_kernel<<<N_TOK, 64, 0, stream>>>(x, gate_w, gate_b, topk_idx, topk_prob, xb);
    hist_kernel<<<NBLK, 256, 0, stream>>>(topk_idx, block_hist);
    scan_tables_kernel<<<1, 1, 0, stream>>>(block_hist, t1_e, t1_rs, t1_rows, block_base);
    scatter_kernel<<<NBLK, 256, 0, stream>>>(topk_idx, topk_prob, block_base, row_token, row_prob, tok2row);
    gemm1_kernel<<<MAXT1 * JN1, 512, 0, stream>>>(xb, w1t, b1, t1_e, t1_rs, t1_rows,
                                                  row_token, row_prob, hbuf);
    gemm2_kernel<<<MAXT1 * 6 * KSPLIT, 512, 0, stream>>>(hbuf, w2t, t1_e, t1_rs, t1_rows, eo);
    combine_kernel<<<N_TOK, 192, 0, stream>>>(eo, tok2row, topk_idx, topk_prob, b2, out);
}